// Round 1
// baseline (803.242 us; speedup 1.0000x reference)
//
#include <hip/hip_runtime.h>
#include <math.h>

#define N_TOK 32768
#define LC 128
#define NCHUNK (N_TOK / LC)   // 256

__device__ __forceinline__ float siluf_(float v){ return v / (1.f + __expf(-v)); }
__device__ __forceinline__ float softplusf_(float v){ return v > 20.f ? v : log1pf(__expf(v)); }

__device__ __forceinline__ float waveRed64(float v){
  #pragma unroll
  for (int m = 1; m < 64; m <<= 1) v += __shfl_xor(v, m);
  return v;
}

// ---------- K0: per-row 1/rms of feat ----------
__global__ void k_invrms(const float* __restrict__ feat, float* __restrict__ invr){
  int row = blockIdx.x*4 + (threadIdx.x>>6);
  int lane = threadIdx.x & 63;
  float2 f2 = ((const float2*)feat)[row*64 + lane];
  float ss = waveRed64(f2.x*f2.x + f2.y*f2.y);
  if (lane==0) invr[row] = rsqrtf(ss * (1.f/128.f) + 1e-5f);
}

// ---------- K1: gather + weighted-sum + LayerNorm -> comb ----------
__global__ void k_gather_ln(const float* __restrict__ feat, const int* __restrict__ ridx,
                            const float* __restrict__ gd, const float* __restrict__ g,
                            const float* __restrict__ b, float* __restrict__ comb){
  int row = blockIdx.x*4 + (threadIdx.x>>6);
  int lane = threadIdx.x & 63;
  float ax=0.f, ay=0.f;
  #pragma unroll 4
  for (int k=0;k<16;k++){
    int idx = ridx[row*16+k];
    float w = gd[row*16+k];
    float2 f = ((const float2*)feat)[idx*64 + lane];
    ax += w*f.x; ay += w*f.y;
  }
  float m = waveRed64(ax+ay) * (1.f/128.f);
  float dx = ax-m, dy = ay-m;
  float var = waveRed64(dx*dx+dy*dy) * (1.f/128.f);
  float is = rsqrtf(var + 1e-5f);
  float2 gg = ((const float2*)g)[lane];
  float2 bb = ((const float2*)b)[lane];
  float2 o; o.x = dx*is*gg.x + bb.x; o.y = dy*is*gg.y + bb.y;
  ((float2*)comb)[row*64+lane] = o;
}

// ---------- K2: rmsnorm(feat) @ in_proj_w  -> x (cols<256), silu(z) (cols>=256) ----------
__global__ void __launch_bounds__(256) k_inproj(const float* __restrict__ feat,
        const float* __restrict__ invr, const float* __restrict__ rmsw,
        const float* __restrict__ W, float* __restrict__ bx, float* __restrict__ bsz){
  __shared__ float At[32][129];
  __shared__ float Wc[64][128];
  int r0 = blockIdx.x*32;
  int c0 = blockIdx.y*128;
  int tid = threadIdx.x;
  for (int e = tid; e < 32*128; e += 256){
    int r = e>>7, k = e&127;
    At[r][k] = feat[(r0+r)*128 + k] * rmsw[k] * invr[r0+r];
  }
  float acc[4][4] = {};
  int c4 = (tid&31)*4;
  int r4 = (tid>>5)*4;
  for (int kb = 0; kb < 2; kb++){
    __syncthreads();
    for (int e = tid; e < 64*128; e += 256){
      int kk = e>>7, c = e&127;
      Wc[kk][c] = W[(kb*64+kk)*512 + c0 + c];
    }
    __syncthreads();
    for (int k = 0; k < 64; k++){
      float4 w = *(const float4*)&Wc[k][c4];
      #pragma unroll
      for (int i=0;i<4;i++){
        float a = At[r4+i][kb*64+k];
        acc[i][0] += a*w.x; acc[i][1] += a*w.y; acc[i][2] += a*w.z; acc[i][3] += a*w.w;
      }
    }
  }
  bool isx = (c0 < 256);
  int cc = isx ? (c0 + c4) : (c0 + c4 - 256);
  for (int i=0;i<4;i++){
    int r = r0 + r4 + i;
    float4 v;
    v.x=acc[i][0]; v.y=acc[i][1]; v.z=acc[i][2]; v.w=acc[i][3];
    if (isx){
      *(float4*)&bx[r*256 + cc] = v;
    } else {
      v.x = siluf_(v.x); v.y = siluf_(v.y); v.z = siluf_(v.z); v.w = siluf_(v.w);
      *(float4*)&bsz[r*256 + cc] = v;
    }
  }
}

// ---------- K3: causal depthwise conv (D_CONV=4) + silu -> bxs ----------
__global__ void __launch_bounds__(256) k_conv(const float* __restrict__ bx,
      const float* __restrict__ cw, const float* __restrict__ cb, float* __restrict__ bxs){
  __shared__ float Xs[67][256];
  int r0 = blockIdx.x*64;
  int d = threadIdx.x;
  for (int i=0;i<67;i++){
    int gr = r0 - 3 + i;
    Xs[i][d] = (gr >= 0) ? bx[gr*256 + d] : 0.f;
  }
  __syncthreads();
  float w0=cw[d*4], w1=cw[d*4+1], w2=cw[d*4+2], w3=cw[d*4+3], bb=cb[d];
  float a0=Xs[0][d], a1=Xs[1][d], a2=Xs[2][d];
  for (int t=0;t<64;t++){
    float a3 = Xs[t+3][d];
    float xc = bb + w0*a0 + w1*a1 + w2*a2 + w3*a3;
    bxs[(r0+t)*256 + d] = siluf_(xc);
    a0=a1; a1=a2; a2=a3;
  }
}

// ---------- K4a: dbc = xs @ x_proj_w (256x40, padded to 64 cols) ----------
__global__ void __launch_bounds__(256) k_xproj(const float* __restrict__ bxs,
      const float* __restrict__ xpw, float* __restrict__ dt8,
      float* __restrict__ Bm, float* __restrict__ Cm){
  __shared__ float At[32][257];
  __shared__ float Wc[64][64];
  int r0 = blockIdx.x*32;
  int tid = threadIdx.x;
  for (int e = tid; e < 32*256; e += 256){
    int r = e>>8, k = e&255;
    At[r][k] = bxs[(r0+r)*256 + k];
  }
  float acc[2][4] = {};
  int c4 = (tid&15)*4;
  int r2 = (tid>>4)*2;
  for (int kb=0;kb<4;kb++){
    __syncthreads();
    for (int e=tid; e<64*64; e+=256){
      int kk=e>>6, c=e&63;
      Wc[kk][c] = (c<40) ? xpw[(kb*64+kk)*40 + c] : 0.f;
    }
    __syncthreads();
    for (int k=0;k<64;k++){
      float4 w = *(const float4*)&Wc[k][c4];
      #pragma unroll
      for (int i=0;i<2;i++){
        float a = At[r2+i][kb*64+k];
        acc[i][0]+=a*w.x; acc[i][1]+=a*w.y; acc[i][2]+=a*w.z; acc[i][3]+=a*w.w;
      }
    }
  }
  for (int i=0;i<2;i++){
    int r = r0 + r2 + i;
    #pragma unroll
    for (int j=0;j<4;j++){
      int cg = c4 + j; float v = acc[i][j];
      if (cg < 8) dt8[r*8 + cg] = v;
      else if (cg < 24) Bm[r*16 + cg - 8] = v;
      else if (cg < 40) Cm[r*16 + cg - 24] = v;
    }
  }
}

// ---------- K4b: delta = softplus(dt8 @ dt_proj_w + dt_proj_b) ----------
__global__ void __launch_bounds__(256) k_delta(const float* __restrict__ dt8,
      const float* __restrict__ dtw, const float* __restrict__ dtb, float* __restrict__ delta){
  __shared__ float T8[64][8];
  __shared__ float Wd[8][256];
  int r0 = blockIdx.x*64;
  int tid = threadIdx.x;
  for (int e=tid; e<512; e+=256){ int r=e>>3, c=e&7; T8[r][c] = dt8[(r0+r)*8 + c]; }
  for (int e=tid; e<2048; e+=256){ int j=e>>8, d=e&255; Wd[j][d] = dtw[j*256 + d]; }
  __syncthreads();
  int d = tid;
  float bb = dtb[d];
  for (int r=0;r<64;r++){
    float acc = bb;
    #pragma unroll
    for (int j=0;j<8;j++) acc += T8[r][j]*Wd[j][d];
    delta[(r0+r)*256 + d] = softplusf_(acc);
  }
}

// ---------- K5: scan pass 1 (chunk-local), emits y_partial, P, H ----------
__global__ void __launch_bounds__(256) k_scan1(const float* __restrict__ delta,
      const float* __restrict__ bxs, const float* __restrict__ Bm, const float* __restrict__ Cm,
      const float* __restrict__ A_log, float* __restrict__ ypart,
      float* __restrict__ Pc, float* __restrict__ Hc){
  __shared__ float Dl[128][16];
  __shared__ float Xl[128][16];
  __shared__ float Bl[128][16];
  __shared__ float Cl[128][16];
  __shared__ float Yt[128][16];
  int g = blockIdx.x, d0 = blockIdx.y*16;
  int tid = threadIdx.x;
  int dl_ = tid>>4, s = tid&15;
  int d = d0 + dl_;
  int t0 = g*128;
  for (int e=tid; e<2048; e+=256){
    int rr=e>>4, c=e&15;
    Dl[rr][c] = delta[(t0+rr)*256 + d0 + c];
    Xl[rr][c] = bxs[(t0+rr)*256 + d0 + c];
    Bl[rr][c] = Bm[(t0+rr)*16 + c];
    Cl[rr][c] = Cm[(t0+rr)*16 + c];
  }
  __syncthreads();
  float aP = -__expf(A_log[d*16 + s]);
  float h = 0.f, dsum = 0.f;
  for (int t=0;t<128;t++){
    float dv = Dl[t][dl_];
    float xv = Xl[t][dl_];
    float bv = Bl[t][s];
    float cv = Cl[t][s];
    float a = __expf(dv * aP);
    h = a*h + dv*bv*xv;
    dsum += dv;
    float yv = h * cv;
    yv += __shfl_xor(yv, 1); yv += __shfl_xor(yv, 2);
    yv += __shfl_xor(yv, 4); yv += __shfl_xor(yv, 8);
    if (s==0) Yt[t][dl_] = yv;
  }
  __syncthreads();
  for (int e=tid; e<2048; e+=256){
    int rr=e>>4, c=e&15;
    ypart[(t0+rr)*256 + d0 + c] = Yt[rr][c];
  }
  Pc[g*4096 + d0*16 + tid] = __expf(dsum * aP);
  Hc[g*4096 + d0*16 + tid] = h;
}

// ---------- K6: sequential carry scan across chunks ----------
__global__ void k_carry(const float* __restrict__ Pc, const float* __restrict__ Hc,
                        float* __restrict__ Cr){
  int ch = blockIdx.x*256 + threadIdx.x;
  float c = 0.f;
  for (int g=0; g<NCHUNK; g++){
    Cr[g*4096 + ch] = c;
    c = Pc[g*4096 + ch]*c + Hc[g*4096 + ch];
  }
}

// ---------- K7: scan pass 2 — carry correction + D*x + silu(z) gating (in place on y) ----------
__global__ void __launch_bounds__(256) k_scan2(const float* __restrict__ delta,
      const float* __restrict__ bxs, const float* __restrict__ Cm,
      const float* __restrict__ bsz, const float* __restrict__ A_log,
      const float* __restrict__ Dp, const float* __restrict__ Cr,
      float* __restrict__ y){
  __shared__ float Dl[128][16];
  __shared__ float Xl[128][16];
  __shared__ float Cl[128][16];
  __shared__ float Zl[128][16];
  __shared__ float Yt[128][16];
  int g = blockIdx.x, d0 = blockIdx.y*16;
  int tid = threadIdx.x;
  int dl_ = tid>>4, s = tid&15;
  int d = d0 + dl_;
  int t0 = g*128;
  for (int e=tid; e<2048; e+=256){
    int rr=e>>4, c=e&15;
    Dl[rr][c] = delta[(t0+rr)*256 + d0 + c];
    Xl[rr][c] = bxs[(t0+rr)*256 + d0 + c];
    Cl[rr][c] = Cm[(t0+rr)*16 + c];
    Zl[rr][c] = bsz[(t0+rr)*256 + d0 + c];
    Yt[rr][c] = y[(t0+rr)*256 + d0 + c];
  }
  __syncthreads();
  float aP = -__expf(A_log[d*16 + s]);
  float h0 = Cr[g*4096 + d0*16 + tid];
  float dpar = Dp[d];
  float crun = 0.f;
  for (int t=0;t<128;t++){
    float dv = Dl[t][dl_];
    crun += dv;
    float corr = Cl[t][s] * __expf(aP * crun) * h0;
    corr += __shfl_xor(corr,1); corr += __shfl_xor(corr,2);
    corr += __shfl_xor(corr,4); corr += __shfl_xor(corr,8);
    if (s==0){
      float yv = Yt[t][dl_] + corr;
      yv = (yv + dpar * Xl[t][dl_]) * Zl[t][dl_];
      Yt[t][dl_] = yv;
    }
  }
  __syncthreads();
  for (int e=tid; e<2048; e+=256){
    int rr=e>>4, c=e&15;
    y[(t0+rr)*256 + d0 + c] = Yt[rr][c];
  }
}

// ---------- generic GEMM: out[N,128] = [A1|A2] @ W + bias + resid ----------
__global__ void __launch_bounds__(256) k_gemm128(const float* __restrict__ A1, int K1,
      const float* __restrict__ A2, int K2,
      const float* __restrict__ W, const float* __restrict__ bias,
      const float* __restrict__ resid, float* __restrict__ out){
  __shared__ float At[32][257];
  __shared__ float Wc[64][128];
  int r0 = blockIdx.x*32;
  int tid = threadIdx.x;
  int K = K1 + K2;
  int ksh = (K==256)?8:7;
  for (int e=tid; e<32*K; e+=256){
    int r = e>>ksh, k = e & (K-1);
    At[r][k] = (k<K1) ? A1[(r0+r)*K1 + k] : A2[(r0+r)*K2 + (k-K1)];
  }
  float acc[4][4] = {};
  int c4 = (tid&31)*4;
  int r4 = (tid>>5)*4;
  int nkb = K>>6;
  for (int kb=0;kb<nkb;kb++){
    __syncthreads();
    for (int e=tid; e<8192; e+=256){
      int kk=e>>7, c=e&127;
      Wc[kk][c] = W[(kb*64+kk)*128 + c];
    }
    __syncthreads();
    for (int k=0;k<64;k++){
      float4 w = *(const float4*)&Wc[k][c4];
      int kk = kb*64 + k;
      #pragma unroll
      for (int i=0;i<4;i++){
        float a = At[r4+i][kk];
        acc[i][0]+=a*w.x; acc[i][1]+=a*w.y; acc[i][2]+=a*w.z; acc[i][3]+=a*w.w;
      }
    }
  }
  float4 bs; bs.x=0.f; bs.y=0.f; bs.z=0.f; bs.w=0.f;
  if (bias) bs = *(const float4*)&bias[c4];
  for (int i=0;i<4;i++){
    int r = r0 + r4 + i;
    float4 v;
    v.x = acc[i][0] + bs.x; v.y = acc[i][1] + bs.y; v.z = acc[i][2] + bs.z; v.w = acc[i][3] + bs.w;
    if (resid){
      float4 rr = *(const float4*)&resid[r*128 + c4];
      v.x += rr.x; v.y += rr.y; v.z += rr.z; v.w += rr.w;
    }
    *(float4*)&out[r*128 + c4] = v;
  }
}

// ---------- generic LayerNorm (optional relu) ----------
__global__ void k_ln(const float* __restrict__ in, const float* __restrict__ g,
                     const float* __restrict__ b, float* __restrict__ out, int dorelu){
  int row = blockIdx.x*4 + (threadIdx.x>>6);
  int lane = threadIdx.x & 63;
  float2 v = ((const float2*)in)[row*64 + lane];
  float m = waveRed64(v.x+v.y) * (1.f/128.f);
  float dx = v.x - m, dy = v.y - m;
  float var = waveRed64(dx*dx + dy*dy) * (1.f/128.f);
  float is = rsqrtf(var + 1e-5f);
  float2 gg = ((const float2*)g)[lane];
  float2 bb = ((const float2*)b)[lane];
  float2 o;
  o.x = dx*is*gg.x + bb.x;
  o.y = dy*is*gg.y + bb.y;
  if (dorelu){ o.x = fmaxf(o.x, 0.f); o.y = fmaxf(o.y, 0.f); }
  ((float2*)out)[row*64 + lane] = o;
}

extern "C" void kernel_launch(void* const* d_in, const int* in_sizes, int n_in,
                              void* d_out, int out_size, void* d_ws, size_t ws_size,
                              hipStream_t stream){
  const float* feat = (const float*)d_in[0];
  const int*   ridx = (const int*)d_in[2];
  const float* gd   = (const float*)d_in[3];
  const float* ipw  = (const float*)d_in[5];
  const float* cw   = (const float*)d_in[6];
  const float* cb   = (const float*)d_in[7];
  const float* xpw  = (const float*)d_in[8];
  const float* dtw  = (const float*)d_in[9];
  const float* dtb  = (const float*)d_in[10];
  const float* alog = (const float*)d_in[11];
  const float* dpar = (const float*)d_in[12];
  const float* opw  = (const float*)d_in[13];
  const float* rmsw = (const float*)d_in[14];
  const float* lng  = (const float*)d_in[15];
  const float* lnb  = (const float*)d_in[16];
  const float* w1   = (const float*)d_in[17];
  const float* b1   = (const float*)d_in[18];
  const float* lag  = (const float*)d_in[19];
  const float* lab  = (const float*)d_in[20];
  const float* w2   = (const float*)d_in[21];
  const float* b2   = (const float*)d_in[22];
  float* out = (float*)d_out;

  float* ws    = (float*)d_ws;
  float* invr  = ws;                       // 32768
  float* bx    = invr + 32768;             // N*256  (pre-conv x; later reused as y)
  float* bsz   = bx   + N_TOK*256;         // N*256  silu(z)
  float* bxs   = bsz  + N_TOK*256;         // N*256  silu(conv(x))
  float* delta = bxs  + N_TOK*256;         // N*256
  float* dt8   = delta + N_TOK*256;        // N*8
  float* Bm    = dt8  + N_TOK*8;           // N*16
  float* Cm    = Bm   + N_TOK*16;          // N*16
  float* comb  = Cm   + N_TOK*16;          // N*128
  float* Pc    = comb + N_TOK*128;         // NCHUNK*4096
  float* Hc    = Pc   + NCHUNK*4096;       // NCHUNK*4096
  float* Cr    = Hc   + NCHUNK*4096;       // NCHUNK*4096
  // aliases (regions free after the scan):
  float* t1    = delta;  // pre-LN scratch
  float* mamba = bsz;    // LN(mamba) output
  float* h1    = bxs;    // relu(LN(...)) output

  hipLaunchKernelGGL(k_invrms,    dim3(N_TOK/4), dim3(256), 0, stream, feat, invr);
  hipLaunchKernelGGL(k_gather_ln, dim3(N_TOK/4), dim3(256), 0, stream, feat, ridx, gd, lng, lnb, comb);
  hipLaunchKernelGGL(k_inproj,    dim3(N_TOK/32, 4), dim3(256), 0, stream, feat, invr, rmsw, ipw, bx, bsz);
  hipLaunchKernelGGL(k_conv,      dim3(N_TOK/64), dim3(256), 0, stream, bx, cw, cb, bxs);
  hipLaunchKernelGGL(k_xproj,     dim3(N_TOK/32), dim3(256), 0, stream, bxs, xpw, dt8, Bm, Cm);
  hipLaunchKernelGGL(k_delta,     dim3(N_TOK/64), dim3(256), 0, stream, dt8, dtw, dtb, delta);
  hipLaunchKernelGGL(k_scan1,     dim3(NCHUNK, 16), dim3(256), 0, stream, delta, bxs, Bm, Cm, alog, bx, Pc, Hc);
  hipLaunchKernelGGL(k_carry,     dim3(16), dim3(256), 0, stream, Pc, Hc, Cr);
  hipLaunchKernelGGL(k_scan2,     dim3(NCHUNK, 16), dim3(256), 0, stream, delta, bxs, Cm, bsz, alog, dpar, Cr, bx);
  hipLaunchKernelGGL(k_gemm128,   dim3(N_TOK/32), dim3(256), 0, stream, bx, 256, (const float*)nullptr, 0, opw, (const float*)nullptr, feat, t1);
  hipLaunchKernelGGL(k_ln,        dim3(N_TOK/4), dim3(256), 0, stream, t1, lng, lnb, mamba, 0);
  hipLaunchKernelGGL(k_gemm128,   dim3(N_TOK/32), dim3(256), 0, stream, mamba, 128, comb, 128, w1, b1, (const float*)nullptr, t1);
  hipLaunchKernelGGL(k_ln,        dim3(N_TOK/4), dim3(256), 0, stream, t1, lag, lab, h1, 1);
  hipLaunchKernelGGL(k_gemm128,   dim3(N_TOK/32), dim3(256), 0, stream, h1, 128, (const float*)nullptr, 0, w2, b2, (const float*)nullptr, out);
}

// Round 2
// 613.455 us; speedup vs baseline: 1.3094x; 1.3094x over previous
//
#include <hip/hip_runtime.h>
#include <math.h>

#define N_TOK 32768
#define LC 128
#define NCHUNK (N_TOK / LC)   // 256
#define T_TILE 32

__device__ __forceinline__ float siluf_(float v){ return v / (1.f + __expf(-v)); }
__device__ __forceinline__ float softplusf_(float v){ return v > 20.f ? v : log1pf(__expf(v)); }

__device__ __forceinline__ float waveRed64(float v){
  #pragma unroll
  for (int m = 1; m < 64; m <<= 1) v += __shfl_xor(v, m);
  return v;
}

// ---------- K0: per-row 1/rms of feat ----------
__global__ void k_invrms(const float* __restrict__ feat, float* __restrict__ invr){
  int row = blockIdx.x*4 + (threadIdx.x>>6);
  int lane = threadIdx.x & 63;
  float2 f2 = ((const float2*)feat)[row*64 + lane];
  float ss = waveRed64(f2.x*f2.x + f2.y*f2.y);
  if (lane==0) invr[row] = rsqrtf(ss * (1.f/128.f) + 1e-5f);
}

// ---------- K1: gather + weighted-sum + LayerNorm -> comb ----------
__global__ void k_gather_ln(const float* __restrict__ feat, const int* __restrict__ ridx,
                            const float* __restrict__ gd, const float* __restrict__ g,
                            const float* __restrict__ b, float* __restrict__ comb){
  int row = blockIdx.x*4 + (threadIdx.x>>6);
  int lane = threadIdx.x & 63;
  float ax=0.f, ay=0.f;
  #pragma unroll 4
  for (int k=0;k<16;k++){
    int idx = ridx[row*16+k];
    float w = gd[row*16+k];
    float2 f = ((const float2*)feat)[idx*64 + lane];
    ax += w*f.x; ay += w*f.y;
  }
  float m = waveRed64(ax+ay) * (1.f/128.f);
  float dx = ax-m, dy = ay-m;
  float var = waveRed64(dx*dx+dy*dy) * (1.f/128.f);
  float is = rsqrtf(var + 1e-5f);
  float2 gg = ((const float2*)g)[lane];
  float2 bb = ((const float2*)b)[lane];
  float2 o; o.x = dx*is*gg.x + bb.x; o.y = dy*is*gg.y + bb.y;
  ((float2*)comb)[row*64+lane] = o;
}

// ---------- K2: rmsnorm(feat) @ in_proj_w  -> x (cols<256), silu(z) (cols>=256) ----------
__global__ void __launch_bounds__(256) k_inproj(const float* __restrict__ feat,
        const float* __restrict__ invr, const float* __restrict__ rmsw,
        const float* __restrict__ W, float* __restrict__ bx, float* __restrict__ bsz){
  __shared__ float At[32][129];
  __shared__ float Wc[64][128];
  int r0 = blockIdx.x*32;
  int c0 = blockIdx.y*128;
  int tid = threadIdx.x;
  for (int e = tid; e < 32*128; e += 256){
    int r = e>>7, k = e&127;
    At[r][k] = feat[(r0+r)*128 + k] * rmsw[k] * invr[r0+r];
  }
  float acc[4][4] = {};
  int c4 = (tid&31)*4;
  int r4 = (tid>>5)*4;
  for (int kb = 0; kb < 2; kb++){
    __syncthreads();
    for (int e = tid; e < 64*128; e += 256){
      int kk = e>>7, c = e&127;
      Wc[kk][c] = W[(kb*64+kk)*512 + c0 + c];
    }
    __syncthreads();
    for (int k = 0; k < 64; k++){
      float4 w = *(const float4*)&Wc[k][c4];
      #pragma unroll
      for (int i=0;i<4;i++){
        float a = At[r4+i][kb*64+k];
        acc[i][0] += a*w.x; acc[i][1] += a*w.y; acc[i][2] += a*w.z; acc[i][3] += a*w.w;
      }
    }
  }
  bool isx = (c0 < 256);
  int cc = isx ? (c0 + c4) : (c0 + c4 - 256);
  for (int i=0;i<4;i++){
    int r = r0 + r4 + i;
    float4 v;
    v.x=acc[i][0]; v.y=acc[i][1]; v.z=acc[i][2]; v.w=acc[i][3];
    if (isx){
      *(float4*)&bx[r*256 + cc] = v;
    } else {
      v.x = siluf_(v.x); v.y = siluf_(v.y); v.z = siluf_(v.z); v.w = siluf_(v.w);
      *(float4*)&bsz[r*256 + cc] = v;
    }
  }
}

// ---------- K3: causal depthwise conv (D_CONV=4) + silu -> bxs ----------
__global__ void __launch_bounds__(256) k_conv(const float* __restrict__ bx,
      const float* __restrict__ cw, const float* __restrict__ cb, float* __restrict__ bxs){
  __shared__ float Xs[67][256];
  int r0 = blockIdx.x*64;
  int d = threadIdx.x;
  for (int i=0;i<67;i++){
    int gr = r0 - 3 + i;
    Xs[i][d] = (gr >= 0) ? bx[gr*256 + d] : 0.f;
  }
  __syncthreads();
  float w0=cw[d*4], w1=cw[d*4+1], w2=cw[d*4+2], w3=cw[d*4+3], bb=cb[d];
  float a0=Xs[0][d], a1=Xs[1][d], a2=Xs[2][d];
  for (int t=0;t<64;t++){
    float a3 = Xs[t+3][d];
    float xc = bb + w0*a0 + w1*a1 + w2*a2 + w3*a3;
    bxs[(r0+t)*256 + d] = siluf_(xc);
    a0=a1; a1=a2; a2=a3;
  }
}

// ---------- K4a: dbc = xs @ x_proj_w (256x40, padded to 64 cols) ----------
__global__ void __launch_bounds__(256) k_xproj(const float* __restrict__ bxs,
      const float* __restrict__ xpw, float* __restrict__ dt8,
      float* __restrict__ Bm, float* __restrict__ Cm){
  __shared__ float At[32][257];
  __shared__ float Wc[64][64];
  int r0 = blockIdx.x*32;
  int tid = threadIdx.x;
  for (int e = tid; e < 32*256; e += 256){
    int r = e>>8, k = e&255;
    At[r][k] = bxs[(r0+r)*256 + k];
  }
  float acc[2][4] = {};
  int c4 = (tid&15)*4;
  int r2 = (tid>>4)*2;
  for (int kb=0;kb<4;kb++){
    __syncthreads();
    for (int e=tid; e<64*64; e+=256){
      int kk=e>>6, c=e&63;
      Wc[kk][c] = (c<40) ? xpw[(kb*64+kk)*40 + c] : 0.f;
    }
    __syncthreads();
    for (int k=0;k<64;k++){
      float4 w = *(const float4*)&Wc[k][c4];
      #pragma unroll
      for (int i=0;i<2;i++){
        float a = At[r2+i][kb*64+k];
        acc[i][0]+=a*w.x; acc[i][1]+=a*w.y; acc[i][2]+=a*w.z; acc[i][3]+=a*w.w;
      }
    }
  }
  for (int i=0;i<2;i++){
    int r = r0 + r2 + i;
    #pragma unroll
    for (int j=0;j<4;j++){
      int cg = c4 + j; float v = acc[i][j];
      if (cg < 8) dt8[r*8 + cg] = v;
      else if (cg < 24) Bm[r*16 + cg - 8] = v;
      else if (cg < 40) Cm[r*16 + cg - 24] = v;
    }
  }
}

// ---------- K4b: delta = softplus(dt8 @ dt_proj_w + dt_proj_b) ----------
__global__ void __launch_bounds__(256) k_delta(const float* __restrict__ dt8,
      const float* __restrict__ dtw, const float* __restrict__ dtb, float* __restrict__ delta){
  __shared__ float T8[64][8];
  __shared__ float Wd[8][256];
  int r0 = blockIdx.x*64;
  int tid = threadIdx.x;
  for (int e=tid; e<512; e+=256){ int r=e>>3, c=e&7; T8[r][c] = dt8[(r0+r)*8 + c]; }
  for (int e=tid; e<2048; e+=256){ int j=e>>8, d=e&255; Wd[j][d] = dtw[j*256 + d]; }
  __syncthreads();
  int d = tid;
  float bb = dtb[d];
  for (int r=0;r<64;r++){
    float acc = bb;
    #pragma unroll
    for (int j=0;j<8;j++) acc += T8[r][j]*Wd[j][d];
    delta[(r0+r)*256 + d] = softplusf_(acc);
  }
}

// ---------- K5: scan pass 1 — one thread per channel d, h[16] in regs.
// Emits chunk-final state H and chunk decay P only (no y). ----------
__global__ void __launch_bounds__(256) k_scan1(const float* __restrict__ delta,
      const float* __restrict__ bxs, const float* __restrict__ Bm,
      const float* __restrict__ A_log, float* __restrict__ Pc, float* __restrict__ Hc){
  __shared__ float Bl[LC][16];        // 8 KB
  __shared__ float Dl[T_TILE][256];   // 32 KB
  __shared__ float Xl[T_TILE][256];   // 32 KB
  int g = blockIdx.x;
  int d = threadIdx.x;
  int t0 = g*LC;
  {
    const float4* src = (const float4*)(Bm + t0*16);
    float4* dst = (float4*)&Bl[0][0];
    for (int e=d; e<LC*16/4; e+=256) dst[e] = src[e];
  }
  float aS[16];
  #pragma unroll
  for (int s=0;s<16;s++) aS[s] = -__expf(A_log[d*16+s]);
  float h[16];
  #pragma unroll
  for (int s=0;s<16;s++) h[s] = 0.f;
  float dsum = 0.f;
  for (int tile=0; tile<LC/T_TILE; tile++){
    __syncthreads();
    {
      const float4* sd = (const float4*)(delta + (t0+tile*T_TILE)*256);
      const float4* sx = (const float4*)(bxs  + (t0+tile*T_TILE)*256);
      float4* dd = (float4*)&Dl[0][0];
      float4* dx = (float4*)&Xl[0][0];
      for (int e=d; e<T_TILE*64; e+=256){ dd[e]=sd[e]; dx[e]=sx[e]; }
    }
    __syncthreads();
    #pragma unroll 4
    for (int tt=0; tt<T_TILE; tt++){
      float dv = Dl[tt][d];
      float xv = Xl[tt][d];
      dsum += dv;
      float dx_ = dv*xv;
      int t = tile*T_TILE+tt;
      #pragma unroll
      for (int s=0;s<16;s++){
        h[s] = __expf(dv*aS[s])*h[s] + dx_*Bl[t][s];
      }
    }
  }
  float4* Pd = (float4*)(Pc + g*4096 + d*16);
  float4* Hd = (float4*)(Hc + g*4096 + d*16);
  #pragma unroll
  for (int q=0;q<4;q++){
    Pd[q] = make_float4(__expf(dsum*aS[q*4]), __expf(dsum*aS[q*4+1]),
                        __expf(dsum*aS[q*4+2]), __expf(dsum*aS[q*4+3]));
    Hd[q] = make_float4(h[q*4], h[q*4+1], h[q*4+2], h[q*4+3]);
  }
}

// ---------- K6: sequential carry scan across chunks ----------
__global__ void k_carry(const float* __restrict__ Pc, const float* __restrict__ Hc,
                        float* __restrict__ Cr){
  int ch = blockIdx.x*256 + threadIdx.x;
  float c = 0.f;
  for (int g=0; g<NCHUNK; g++){
    Cr[g*4096 + ch] = c;
    c = Pc[g*4096 + ch]*c + Hc[g*4096 + ch];
  }
}

// ---------- K7: scan pass 2 — recompute local scan seeded with carry,
// produce final gated y = (scan + D*x) * silu(z) directly. ----------
__global__ void __launch_bounds__(256) k_scan2(const float* __restrict__ delta,
      const float* __restrict__ bxs, const float* __restrict__ Bm, const float* __restrict__ Cm,
      const float* __restrict__ bsz, const float* __restrict__ A_log,
      const float* __restrict__ Dp, const float* __restrict__ Cr, float* __restrict__ y){
  __shared__ float Bl[LC][16];        // 8 KB
  __shared__ float Cl[LC][16];        // 8 KB
  __shared__ float Dl[T_TILE][256];   // 32 KB
  __shared__ float Xl[T_TILE][256];   // 32 KB
  __shared__ float Zl[T_TILE][256];   // 32 KB  (112 KB total)
  int g = blockIdx.x;
  int d = threadIdx.x;
  int t0 = g*LC;
  {
    const float4* sb = (const float4*)(Bm + t0*16);
    const float4* sc = (const float4*)(Cm + t0*16);
    float4* db = (float4*)&Bl[0][0];
    float4* dc = (float4*)&Cl[0][0];
    for (int e=d; e<LC*16/4; e+=256){ db[e]=sb[e]; dc[e]=sc[e]; }
  }
  float aS[16];
  #pragma unroll
  for (int s=0;s<16;s++) aS[s] = -__expf(A_log[d*16+s]);
  float h[16];
  {
    const float4* hc = (const float4*)(Cr + g*4096 + d*16);
    #pragma unroll
    for (int q=0;q<4;q++){
      float4 v = hc[q];
      h[q*4]=v.x; h[q*4+1]=v.y; h[q*4+2]=v.z; h[q*4+3]=v.w;
    }
  }
  float dpar = Dp[d];
  for (int tile=0; tile<LC/T_TILE; tile++){
    __syncthreads();
    {
      const float4* sd = (const float4*)(delta + (t0+tile*T_TILE)*256);
      const float4* sx = (const float4*)(bxs  + (t0+tile*T_TILE)*256);
      const float4* sz = (const float4*)(bsz  + (t0+tile*T_TILE)*256);
      float4* dd = (float4*)&Dl[0][0];
      float4* dx = (float4*)&Xl[0][0];
      float4* dz = (float4*)&Zl[0][0];
      for (int e=d; e<T_TILE*64; e+=256){ dd[e]=sd[e]; dx[e]=sx[e]; dz[e]=sz[e]; }
    }
    __syncthreads();
    #pragma unroll 4
    for (int tt=0; tt<T_TILE; tt++){
      float dv = Dl[tt][d];
      float xv = Xl[tt][d];
      float zv = Zl[tt][d];
      float dx_ = dv*xv;
      int t = tile*T_TILE+tt;
      float yv = 0.f;
      #pragma unroll
      for (int s=0;s<16;s++){
        h[s] = __expf(dv*aS[s])*h[s] + dx_*Bl[t][s];
        yv += h[s]*Cl[t][s];
      }
      y[(t0+t)*256 + d] = (yv + dpar*xv)*zv;
    }
  }
}

// ---------- generic GEMM: out[N,128] = [A1|A2] @ W + bias + resid ----------
__global__ void __launch_bounds__(256) k_gemm128(const float* __restrict__ A1, int K1,
      const float* __restrict__ A2, int K2,
      const float* __restrict__ W, const float* __restrict__ bias,
      const float* __restrict__ resid, float* __restrict__ out){
  __shared__ float At[32][257];
  __shared__ float Wc[64][128];
  int r0 = blockIdx.x*32;
  int tid = threadIdx.x;
  int K = K1 + K2;
  int ksh = (K==256)?8:7;
  for (int e=tid; e<32*K; e+=256){
    int r = e>>ksh, k = e & (K-1);
    At[r][k] = (k<K1) ? A1[(r0+r)*K1 + k] : A2[(r0+r)*K2 + (k-K1)];
  }
  float acc[4][4] = {};
  int c4 = (tid&31)*4;
  int r4 = (tid>>5)*4;
  int nkb = K>>6;
  for (int kb=0;kb<nkb;kb++){
    __syncthreads();
    for (int e=tid; e<8192; e+=256){
      int kk=e>>7, c=e&127;
      Wc[kk][c] = W[(kb*64+kk)*128 + c];
    }
    __syncthreads();
    for (int k=0;k<64;k++){
      float4 w = *(const float4*)&Wc[k][c4];
      int kk = kb*64 + k;
      #pragma unroll
      for (int i=0;i<4;i++){
        float a = At[r4+i][kk];
        acc[i][0]+=a*w.x; acc[i][1]+=a*w.y; acc[i][2]+=a*w.z; acc[i][3]+=a*w.w;
      }
    }
  }
  float4 bs; bs.x=0.f; bs.y=0.f; bs.z=0.f; bs.w=0.f;
  if (bias) bs = *(const float4*)&bias[c4];
  for (int i=0;i<4;i++){
    int r = r0 + r4 + i;
    float4 v;
    v.x = acc[i][0] + bs.x; v.y = acc[i][1] + bs.y; v.z = acc[i][2] + bs.z; v.w = acc[i][3] + bs.w;
    if (resid){
      float4 rr = *(const float4*)&resid[r*128 + c4];
      v.x += rr.x; v.y += rr.y; v.z += rr.z; v.w += rr.w;
    }
    *(float4*)&out[r*128 + c4] = v;
  }
}

// ---------- generic LayerNorm (optional relu) ----------
__global__ void k_ln(const float* __restrict__ in, const float* __restrict__ g,
                     const float* __restrict__ b, float* __restrict__ out, int dorelu){
  int row = blockIdx.x*4 + (threadIdx.x>>6);
  int lane = threadIdx.x & 63;
  float2 v = ((const float2*)in)[row*64 + lane];
  float m = waveRed64(v.x+v.y) * (1.f/128.f);
  float dx = v.x - m, dy = v.y - m;
  float var = waveRed64(dx*dx + dy*dy) * (1.f/128.f);
  float is = rsqrtf(var + 1e-5f);
  float2 gg = ((const float2*)g)[lane];
  float2 bb = ((const float2*)b)[lane];
  float2 o;
  o.x = dx*is*gg.x + bb.x;
  o.y = dy*is*gg.y + bb.y;
  if (dorelu){ o.x = fmaxf(o.x, 0.f); o.y = fmaxf(o.y, 0.f); }
  ((float2*)out)[row*64 + lane] = o;
}

extern "C" void kernel_launch(void* const* d_in, const int* in_sizes, int n_in,
                              void* d_out, int out_size, void* d_ws, size_t ws_size,
                              hipStream_t stream){
  const float* feat = (const float*)d_in[0];
  const int*   ridx = (const int*)d_in[2];
  const float* gd   = (const float*)d_in[3];
  const float* ipw  = (const float*)d_in[5];
  const float* cw   = (const float*)d_in[6];
  const float* cb   = (const float*)d_in[7];
  const float* xpw  = (const float*)d_in[8];
  const float* dtw  = (const float*)d_in[9];
  const float* dtb  = (const float*)d_in[10];
  const float* alog = (const float*)d_in[11];
  const float* dpar = (const float*)d_in[12];
  const float* opw  = (const float*)d_in[13];
  const float* rmsw = (const float*)d_in[14];
  const float* lng  = (const float*)d_in[15];
  const float* lnb  = (const float*)d_in[16];
  const float* w1   = (const float*)d_in[17];
  const float* b1   = (const float*)d_in[18];
  const float* lag  = (const float*)d_in[19];
  const float* lab  = (const float*)d_in[20];
  const float* w2   = (const float*)d_in[21];
  const float* b2   = (const float*)d_in[22];
  float* out = (float*)d_out;

  float* ws    = (float*)d_ws;
  float* invr  = ws;                       // 32768
  float* bx    = invr + 32768;             // N*256  (pre-conv x; later final gated y)
  float* bsz   = bx   + N_TOK*256;         // N*256  silu(z)
  float* bxs   = bsz  + N_TOK*256;         // N*256  silu(conv(x))
  float* delta = bxs  + N_TOK*256;         // N*256
  float* dt8   = delta + N_TOK*256;        // N*8
  float* Bm    = dt8  + N_TOK*8;           // N*16
  float* Cm    = Bm   + N_TOK*16;          // N*16
  float* comb  = Cm   + N_TOK*16;          // N*128
  float* Pc    = comb + N_TOK*128;         // NCHUNK*4096
  float* Hc    = Pc   + NCHUNK*4096;       // NCHUNK*4096
  float* Cr    = Hc   + NCHUNK*4096;       // NCHUNK*4096
  // aliases (regions free after the scan):
  float* t1    = delta;  // pre-LN scratch
  float* mamba = bsz;    // LN(mamba) output
  float* h1    = bxs;    // relu(LN(...)) output

  hipLaunchKernelGGL(k_invrms,    dim3(N_TOK/4), dim3(256), 0, stream, feat, invr);
  hipLaunchKernelGGL(k_gather_ln, dim3(N_TOK/4), dim3(256), 0, stream, feat, ridx, gd, lng, lnb, comb);
  hipLaunchKernelGGL(k_inproj,    dim3(N_TOK/32, 4), dim3(256), 0, stream, feat, invr, rmsw, ipw, bx, bsz);
  hipLaunchKernelGGL(k_conv,      dim3(N_TOK/64), dim3(256), 0, stream, bx, cw, cb, bxs);
  hipLaunchKernelGGL(k_xproj,     dim3(N_TOK/32), dim3(256), 0, stream, bxs, xpw, dt8, Bm, Cm);
  hipLaunchKernelGGL(k_delta,     dim3(N_TOK/64), dim3(256), 0, stream, dt8, dtw, dtb, delta);
  hipLaunchKernelGGL(k_scan1,     dim3(NCHUNK), dim3(256), 0, stream, delta, bxs, Bm, alog, Pc, Hc);
  hipLaunchKernelGGL(k_carry,     dim3(16), dim3(256), 0, stream, Pc, Hc, Cr);
  hipLaunchKernelGGL(k_scan2,     dim3(NCHUNK), dim3(256), 0, stream, delta, bxs, Bm, Cm, bsz, alog, dpar, Cr, bx);
  hipLaunchKernelGGL(k_gemm128,   dim3(N_TOK/32), dim3(256), 0, stream, bx, 256, (const float*)nullptr, 0, opw, (const float*)nullptr, feat, t1);
  hipLaunchKernelGGL(k_ln,        dim3(N_TOK/4), dim3(256), 0, stream, t1, lng, lnb, mamba, 0);
  hipLaunchKernelGGL(k_gemm128,   dim3(N_TOK/32), dim3(256), 0, stream, mamba, 128, comb, 128, w1, b1, (const float*)nullptr, t1);
  hipLaunchKernelGGL(k_ln,        dim3(N_TOK/4), dim3(256), 0, stream, t1, lag, lab, h1, 1);
  hipLaunchKernelGGL(k_gemm128,   dim3(N_TOK/32), dim3(256), 0, stream, h1, 128, (const float*)nullptr, 0, w2, b2, (const float*)nullptr, out);
}

// Round 3
// 488.698 us; speedup vs baseline: 1.6436x; 1.2553x over previous
//
#include <hip/hip_runtime.h>
#include <hip/hip_bf16.h>
#include <math.h>

#define N_TOK 32768
#define LC 128
#define NCHUNK (N_TOK / LC)   // 256
#define T_TILE 32

typedef short short8 __attribute__((ext_vector_type(8)));   // 8 bf16 (4 VGPRs)
typedef float f32x4 __attribute__((ext_vector_type(4)));

__device__ __forceinline__ float siluf_(float v){ return v / (1.f + __expf(-v)); }
__device__ __forceinline__ float softplusf_(float v){ return v > 20.f ? v : log1pf(__expf(v)); }

__device__ __forceinline__ unsigned f2bfu(float f){
  __hip_bfloat16 h = __float2bfloat16(f);
  return (unsigned)*(unsigned short*)&h;
}

__device__ __forceinline__ float waveRed64(float v){
  #pragma unroll
  for (int m = 1; m < 64; m <<= 1) v += __shfl_xor(v, m);
  return v;
}

// ---------- W convert+transpose: wt[n*K+k] = bf16(w[k*N+n]) ----------
__global__ void k_wcvt(const float* __restrict__ w, __hip_bfloat16* __restrict__ wt, int K, int N){
  int e = blockIdx.x*256 + threadIdx.x;
  if (e >= K*N) return;
  int n = e / K, k = e % K;
  wt[e] = __float2bfloat16(w[k*N + n]);
}

// ---------- K0: a0 = bf16(rmsnorm(feat)) ----------
__global__ void k_rms_bf16(const float* __restrict__ feat, const float* __restrict__ rmsw,
                           unsigned* __restrict__ a0u){
  int row = blockIdx.x*4 + (threadIdx.x>>6);
  int lane = threadIdx.x & 63;
  float2 f2 = ((const float2*)feat)[row*64 + lane];
  float ss = waveRed64(f2.x*f2.x + f2.y*f2.y);
  float is = rsqrtf(ss * (1.f/128.f) + 1e-5f);
  float2 w = ((const float2*)rmsw)[lane];
  a0u[row*64 + lane] = f2bfu(f2.x*is*w.x) | (f2bfu(f2.y*is*w.y) << 16);
}

// ---------- K1: gather + weighted-sum + LayerNorm -> cat[:,128:256] (bf16) ----------
__global__ void k_gather_ln(const float* __restrict__ feat, const int* __restrict__ ridx,
                            const float* __restrict__ gd, const float* __restrict__ g,
                            const float* __restrict__ b, unsigned* __restrict__ catu){
  int row = blockIdx.x*4 + (threadIdx.x>>6);
  int lane = threadIdx.x & 63;
  float ax=0.f, ay=0.f;
  #pragma unroll 4
  for (int k=0;k<16;k++){
    int idx = ridx[row*16+k];
    float w = gd[row*16+k];
    float2 f = ((const float2*)feat)[idx*64 + lane];
    ax += w*f.x; ay += w*f.y;
  }
  float m = waveRed64(ax+ay) * (1.f/128.f);
  float dx = ax-m, dy = ay-m;
  float var = waveRed64(dx*dx+dy*dy) * (1.f/128.f);
  float is = rsqrtf(var + 1e-5f);
  float2 gg = ((const float2*)g)[lane];
  float2 bb = ((const float2*)b)[lane];
  float ox = dx*is*gg.x + bb.x, oy = dy*is*gg.y + bb.y;
  catu[row*128 + 64 + lane] = f2bfu(ox) | (f2bfu(oy) << 16);   // cols 128..255 of cat
}

// ---------- MFMA GEMM: out[M,N] = A[M,K](bf16) @ Wt[N,K](bf16)^T ----------
// MODE 0: + bias? + resid? -> out0[m*ldout+n]
// MODE 1: n<256 -> out0 (x); n>=256 -> silu -> out1 (z)   (in_proj)
template<int WM16, int WN16, int MODE>
__global__ __launch_bounds__(256) void k_mfma(const __hip_bfloat16* __restrict__ A,
      const __hip_bfloat16* __restrict__ Wt, int K,
      const float* __restrict__ bias, const float* __restrict__ resid,
      float* __restrict__ out0, float* __restrict__ out1, int ldout){
  int tid = threadIdx.x;
  int wave = tid>>6, lane = tid&63;
  int wm = wave>>1, wn = wave&1;
  int lane16 = lane&15, quad = lane>>4;
  int m_w = blockIdx.x*(2*WM16*16) + wm*(WM16*16);
  int n_w = blockIdx.y*(2*WN16*16) + wn*(WN16*16);
  f32x4 acc[WM16][WN16];
  #pragma unroll
  for (int i=0;i<WM16;i++)
    #pragma unroll
    for (int j=0;j<WN16;j++) acc[i][j] = (f32x4){0.f,0.f,0.f,0.f};
  const __hip_bfloat16* Ab = A  + (size_t)(m_w + lane16)*K + quad*8;
  const __hip_bfloat16* Bb = Wt + (size_t)(n_w + lane16)*K + quad*8;
  #pragma unroll 4
  for (int kk=0; kk<K; kk+=32){
    short8 a[WM16], b[WN16];
    #pragma unroll
    for (int i=0;i<WM16;i++) a[i] = *(const short8*)(Ab + (size_t)i*16*K + kk);
    #pragma unroll
    for (int j=0;j<WN16;j++) b[j] = *(const short8*)(Bb + (size_t)j*16*K + kk);
    #pragma unroll
    for (int i=0;i<WM16;i++)
      #pragma unroll
      for (int j=0;j<WN16;j++)
        acc[i][j] = __builtin_amdgcn_mfma_f32_16x16x32_bf16(a[i], b[j], acc[i][j], 0, 0, 0);
  }
  #pragma unroll
  for (int i=0;i<WM16;i++){
    #pragma unroll
    for (int j=0;j<WN16;j++){
      int n = n_w + j*16 + lane16;
      float bv = 0.f;
      if (MODE==0 && bias) bv = bias[n];
      #pragma unroll
      for (int r=0;r<4;r++){
        int m = m_w + i*16 + quad*4 + r;
        float v = acc[i][j][r] + bv;
        if (MODE==0){
          if (resid) v += resid[(size_t)m*ldout + n];
          out0[(size_t)m*ldout + n] = v;
        } else {
          if (n < 256) out0[(size_t)m*256 + n] = v;
          else         out1[(size_t)m*256 + (n-256)] = siluf_(v);
        }
      }
    }
  }
}

// ---------- K3: causal depthwise conv (D_CONV=4) + silu -> bxs ----------
__global__ void __launch_bounds__(256) k_conv(const float* __restrict__ bx,
      const float* __restrict__ cw, const float* __restrict__ cb, float* __restrict__ bxs){
  __shared__ float Xs[67][256];
  int r0 = blockIdx.x*64;
  int d = threadIdx.x;
  for (int i=0;i<67;i++){
    int gr = r0 - 3 + i;
    Xs[i][d] = (gr >= 0) ? bx[gr*256 + d] : 0.f;
  }
  __syncthreads();
  float w0=cw[d*4], w1=cw[d*4+1], w2=cw[d*4+2], w3=cw[d*4+3], bb=cb[d];
  float a0=Xs[0][d], a1=Xs[1][d], a2=Xs[2][d];
  for (int t=0;t<64;t++){
    float a3 = Xs[t+3][d];
    float xc = bb + w0*a0 + w1*a1 + w2*a2 + w3*a3;
    bxs[(r0+t)*256 + d] = siluf_(xc);
    a0=a1; a1=a2; a2=a3;
  }
}

// ---------- K4a: dbc = xs @ x_proj_w (256x40, padded to 64 cols) ----------
__global__ void __launch_bounds__(256) k_xproj(const float* __restrict__ bxs,
      const float* __restrict__ xpw, float* __restrict__ dt8,
      float* __restrict__ Bm, float* __restrict__ Cm){
  __shared__ float At[32][257];
  __shared__ float Wc[64][64];
  int r0 = blockIdx.x*32;
  int tid = threadIdx.x;
  for (int e = tid; e < 32*256; e += 256){
    int r = e>>8, k = e&255;
    At[r][k] = bxs[(r0+r)*256 + k];
  }
  float acc[2][4] = {};
  int c4 = (tid&15)*4;
  int r2 = (tid>>4)*2;
  for (int kb=0;kb<4;kb++){
    __syncthreads();
    for (int e=tid; e<64*64; e+=256){
      int kk=e>>6, c=e&63;
      Wc[kk][c] = (c<40) ? xpw[(kb*64+kk)*40 + c] : 0.f;
    }
    __syncthreads();
    for (int k=0;k<64;k++){
      float4 w = *(const float4*)&Wc[k][c4];
      #pragma unroll
      for (int i=0;i<2;i++){
        float a = At[r2+i][kb*64+k];
        acc[i][0]+=a*w.x; acc[i][1]+=a*w.y; acc[i][2]+=a*w.z; acc[i][3]+=a*w.w;
      }
    }
  }
  for (int i=0;i<2;i++){
    int r = r0 + r2 + i;
    #pragma unroll
    for (int j=0;j<4;j++){
      int cg = c4 + j; float v = acc[i][j];
      if (cg < 8) dt8[r*8 + cg] = v;
      else if (cg < 24) Bm[r*16 + cg - 8] = v;
      else if (cg < 40) Cm[r*16 + cg - 24] = v;
    }
  }
}

// ---------- K4b: delta = softplus(dt8 @ dt_proj_w + dt_proj_b) ----------
__global__ void __launch_bounds__(256) k_delta(const float* __restrict__ dt8,
      const float* __restrict__ dtw, const float* __restrict__ dtb, float* __restrict__ delta){
  __shared__ float T8[64][8];
  __shared__ float Wd[8][256];
  int r0 = blockIdx.x*64;
  int tid = threadIdx.x;
  for (int e=tid; e<512; e+=256){ int r=e>>3, c=e&7; T8[r][c] = dt8[(r0+r)*8 + c]; }
  for (int e=tid; e<2048; e+=256){ int j=e>>8, d=e&255; Wd[j][d] = dtw[j*256 + d]; }
  __syncthreads();
  int d = tid;
  float bb = dtb[d];
  for (int r=0;r<64;r++){
    float acc = bb;
    #pragma unroll
    for (int j=0;j<8;j++) acc += T8[r][j]*Wd[j][d];
    delta[(r0+r)*256 + d] = softplusf_(acc);
  }
}

// ---------- K5: scan pass 1 — one thread per channel d, h[16] in regs ----------
__global__ void __launch_bounds__(256) k_scan1(const float* __restrict__ delta,
      const float* __restrict__ bxs, const float* __restrict__ Bm,
      const float* __restrict__ A_log, float* __restrict__ Pc, float* __restrict__ Hc){
  __shared__ float Bl[LC][16];
  __shared__ float Dl[T_TILE][256];
  __shared__ float Xl[T_TILE][256];
  int g = blockIdx.x;
  int d = threadIdx.x;
  int t0 = g*LC;
  {
    const float4* src = (const float4*)(Bm + t0*16);
    float4* dst = (float4*)&Bl[0][0];
    for (int e=d; e<LC*16/4; e+=256) dst[e] = src[e];
  }
  float aS[16];
  #pragma unroll
  for (int s=0;s<16;s++) aS[s] = -__expf(A_log[d*16+s]);
  float h[16];
  #pragma unroll
  for (int s=0;s<16;s++) h[s] = 0.f;
  float dsum = 0.f;
  for (int tile=0; tile<LC/T_TILE; tile++){
    __syncthreads();
    {
      const float4* sd = (const float4*)(delta + (t0+tile*T_TILE)*256);
      const float4* sx = (const float4*)(bxs  + (t0+tile*T_TILE)*256);
      float4* dd = (float4*)&Dl[0][0];
      float4* dx = (float4*)&Xl[0][0];
      for (int e=d; e<T_TILE*64; e+=256){ dd[e]=sd[e]; dx[e]=sx[e]; }
    }
    __syncthreads();
    #pragma unroll 4
    for (int tt=0; tt<T_TILE; tt++){
      float dv = Dl[tt][d];
      float xv = Xl[tt][d];
      dsum += dv;
      float dx_ = dv*xv;
      int t = tile*T_TILE+tt;
      #pragma unroll
      for (int s=0;s<16;s++){
        h[s] = __expf(dv*aS[s])*h[s] + dx_*Bl[t][s];
      }
    }
  }
  float4* Pd = (float4*)(Pc + g*4096 + d*16);
  float4* Hd = (float4*)(Hc + g*4096 + d*16);
  #pragma unroll
  for (int q=0;q<4;q++){
    Pd[q] = make_float4(__expf(dsum*aS[q*4]), __expf(dsum*aS[q*4+1]),
                        __expf(dsum*aS[q*4+2]), __expf(dsum*aS[q*4+3]));
    Hd[q] = make_float4(h[q*4], h[q*4+1], h[q*4+2], h[q*4+3]);
  }
}

// ---------- K6: sequential carry scan across chunks ----------
__global__ void k_carry(const float* __restrict__ Pc, const float* __restrict__ Hc,
                        float* __restrict__ Cr){
  int ch = blockIdx.x*256 + threadIdx.x;
  float c = 0.f;
  for (int g=0; g<NCHUNK; g++){
    Cr[g*4096 + ch] = c;
    c = Pc[g*4096 + ch]*c + Hc[g*4096 + ch];
  }
}

// ---------- K7: scan pass 2 — final gated y (bf16) ----------
__global__ void __launch_bounds__(256) k_scan2(const float* __restrict__ delta,
      const float* __restrict__ bxs, const float* __restrict__ Bm, const float* __restrict__ Cm,
      const float* __restrict__ bsz, const float* __restrict__ A_log,
      const float* __restrict__ Dp, const float* __restrict__ Cr,
      __hip_bfloat16* __restrict__ yb){
  __shared__ float Bl[LC][16];
  __shared__ float Cl[LC][16];
  __shared__ float Dl[T_TILE][256];
  __shared__ float Xl[T_TILE][256];
  __shared__ float Zl[T_TILE][256];
  int g = blockIdx.x;
  int d = threadIdx.x;
  int t0 = g*LC;
  {
    const float4* sb = (const float4*)(Bm + t0*16);
    const float4* sc = (const float4*)(Cm + t0*16);
    float4* db = (float4*)&Bl[0][0];
    float4* dc = (float4*)&Cl[0][0];
    for (int e=d; e<LC*16/4; e+=256){ db[e]=sb[e]; dc[e]=sc[e]; }
  }
  float aS[16];
  #pragma unroll
  for (int s=0;s<16;s++) aS[s] = -__expf(A_log[d*16+s]);
  float h[16];
  {
    const float4* hc = (const float4*)(Cr + g*4096 + d*16);
    #pragma unroll
    for (int q=0;q<4;q++){
      float4 v = hc[q];
      h[q*4]=v.x; h[q*4+1]=v.y; h[q*4+2]=v.z; h[q*4+3]=v.w;
    }
  }
  float dpar = Dp[d];
  for (int tile=0; tile<LC/T_TILE; tile++){
    __syncthreads();
    {
      const float4* sd = (const float4*)(delta + (t0+tile*T_TILE)*256);
      const float4* sx = (const float4*)(bxs  + (t0+tile*T_TILE)*256);
      const float4* sz = (const float4*)(bsz  + (t0+tile*T_TILE)*256);
      float4* dd = (float4*)&Dl[0][0];
      float4* dx = (float4*)&Xl[0][0];
      float4* dz = (float4*)&Zl[0][0];
      for (int e=d; e<T_TILE*64; e+=256){ dd[e]=sd[e]; dx[e]=sx[e]; dz[e]=sz[e]; }
    }
    __syncthreads();
    #pragma unroll 4
    for (int tt=0; tt<T_TILE; tt++){
      float dv = Dl[tt][d];
      float xv = Xl[tt][d];
      float zv = Zl[tt][d];
      float dx_ = dv*xv;
      int t = tile*T_TILE+tt;
      float yv = 0.f;
      #pragma unroll
      for (int s=0;s<16;s++){
        h[s] = __expf(dv*aS[s])*h[s] + dx_*Bl[t][s];
        yv += h[s]*Cl[t][s];
      }
      yb[(size_t)(t0+t)*256 + d] = __float2bfloat16((yv + dpar*xv)*zv);
    }
  }
}

// ---------- LayerNorm (fp32 in) -> bf16 out, optional relu ----------
__global__ void k_ln_bf16(const float* __restrict__ in, const float* __restrict__ g,
                          const float* __restrict__ b, unsigned* __restrict__ outu,
                          int ldh_u, int dorelu){
  int row = blockIdx.x*4 + (threadIdx.x>>6);
  int lane = threadIdx.x & 63;
  float2 v = ((const float2*)in)[row*64 + lane];
  float m = waveRed64(v.x+v.y) * (1.f/128.f);
  float dx = v.x - m, dy = v.y - m;
  float var = waveRed64(dx*dx + dy*dy) * (1.f/128.f);
  float is = rsqrtf(var + 1e-5f);
  float2 gg = ((const float2*)g)[lane];
  float2 bb = ((const float2*)b)[lane];
  float ox = dx*is*gg.x + bb.x;
  float oy = dy*is*gg.y + bb.y;
  if (dorelu){ ox = fmaxf(ox, 0.f); oy = fmaxf(oy, 0.f); }
  outu[row*ldh_u + lane] = f2bfu(ox) | (f2bfu(oy) << 16);
}

extern "C" void kernel_launch(void* const* d_in, const int* in_sizes, int n_in,
                              void* d_out, int out_size, void* d_ws, size_t ws_size,
                              hipStream_t stream){
  const float* feat = (const float*)d_in[0];
  const int*   ridx = (const int*)d_in[2];
  const float* gd   = (const float*)d_in[3];
  const float* ipw  = (const float*)d_in[5];
  const float* cw   = (const float*)d_in[6];
  const float* cb   = (const float*)d_in[7];
  const float* xpw  = (const float*)d_in[8];
  const float* dtw  = (const float*)d_in[9];
  const float* dtb  = (const float*)d_in[10];
  const float* alog = (const float*)d_in[11];
  const float* dpar = (const float*)d_in[12];
  const float* opw  = (const float*)d_in[13];
  const float* rmsw = (const float*)d_in[14];
  const float* lng  = (const float*)d_in[15];
  const float* lnb  = (const float*)d_in[16];
  const float* w1   = (const float*)d_in[17];
  const float* b1   = (const float*)d_in[18];
  const float* lag  = (const float*)d_in[19];
  const float* lab  = (const float*)d_in[20];
  const float* w2   = (const float*)d_in[21];
  const float* b2   = (const float*)d_in[22];
  float* out = (float*)d_out;

  float* ws    = (float*)d_ws;
  float* bx    = ws;                       // N*256 fp32 (pre-conv x); later aliased as yb (bf16)
  float* bsz   = bx   + N_TOK*256;         // N*256 fp32 silu(z); later aliased as h1 (bf16)
  float* bxs   = bsz  + N_TOK*256;         // N*256 fp32 silu(conv(x))
  float* delta = bxs  + N_TOK*256;         // N*256 fp32; later aliased as t1 (fp32 N*128)
  float* dt8   = delta + N_TOK*256;        // N*8
  float* Bm    = dt8  + N_TOK*8;           // N*16
  float* Cm    = Bm   + N_TOK*16;          // N*16
  float* Pc    = Cm   + N_TOK*16;          // NCHUNK*4096; earlier aliased as a0 (bf16, with Hc)
  float* Hc    = Pc   + NCHUNK*4096;
  float* Cr    = Hc   + NCHUNK*4096;
  __hip_bfloat16* cat  = (__hip_bfloat16*)(Cr + NCHUNK*4096);  // N*256 bf16
  __hip_bfloat16* ipwt = cat  + (size_t)N_TOK*256;             // 512*128
  __hip_bfloat16* opwt = ipwt + 512*128;                       // 128*256
  __hip_bfloat16* w1t  = opwt + 128*256;                       // 128*256
  __hip_bfloat16* w2t  = w1t  + 128*256;                       // 128*128
  // aliases:
  __hip_bfloat16* a0 = (__hip_bfloat16*)Pc;    // N*128 bf16 (dead before scan1 writes Pc)
  __hip_bfloat16* yb = (__hip_bfloat16*)bx;    // N*256 bf16 (bx dead after conv)
  float*          t1 = delta;                  // N*128 fp32 (delta dead after scan2)
  __hip_bfloat16* h1 = (__hip_bfloat16*)bsz;   // N*128 bf16 (bsz dead after scan2)

  // weight conversion (tiny)
  hipLaunchKernelGGL(k_wcvt, dim3((128*512+255)/256), dim3(256), 0, stream, ipw, ipwt, 128, 512);
  hipLaunchKernelGGL(k_wcvt, dim3((256*128+255)/256), dim3(256), 0, stream, opw, opwt, 256, 128);
  hipLaunchKernelGGL(k_wcvt, dim3((256*128+255)/256), dim3(256), 0, stream, w1, w1t, 256, 128);
  hipLaunchKernelGGL(k_wcvt, dim3((128*128+255)/256), dim3(256), 0, stream, w2, w2t, 128, 128);

  hipLaunchKernelGGL(k_rms_bf16,  dim3(N_TOK/4), dim3(256), 0, stream, feat, rmsw, (unsigned*)a0);
  hipLaunchKernelGGL(k_gather_ln, dim3(N_TOK/4), dim3(256), 0, stream, feat, ridx, gd, lng, lnb, (unsigned*)cat);
  hipLaunchKernelGGL((k_mfma<4,4,1>), dim3(N_TOK/128, 4), dim3(256), 0, stream,
                     a0, ipwt, 128, (const float*)nullptr, (const float*)nullptr, bx, bsz, 256);
  hipLaunchKernelGGL(k_conv,  dim3(N_TOK/64), dim3(256), 0, stream, bx, cw, cb, bxs);
  hipLaunchKernelGGL(k_xproj, dim3(N_TOK/32), dim3(256), 0, stream, bxs, xpw, dt8, Bm, Cm);
  hipLaunchKernelGGL(k_delta, dim3(N_TOK/64), dim3(256), 0, stream, dt8, dtw, dtb, delta);
  hipLaunchKernelGGL(k_scan1, dim3(NCHUNK), dim3(256), 0, stream, delta, bxs, Bm, alog, Pc, Hc);
  hipLaunchKernelGGL(k_carry, dim3(16), dim3(256), 0, stream, Pc, Hc, Cr);
  hipLaunchKernelGGL(k_scan2, dim3(NCHUNK), dim3(256), 0, stream, delta, bxs, Bm, Cm, bsz, alog, dpar, Cr, yb);
  hipLaunchKernelGGL((k_mfma<2,4,0>), dim3(N_TOK/64, 1), dim3(256), 0, stream,
                     yb, opwt, 256, (const float*)nullptr, feat, t1, (float*)nullptr, 128);
  hipLaunchKernelGGL(k_ln_bf16, dim3(N_TOK/4), dim3(256), 0, stream, t1, lng, lnb, (unsigned*)cat, 128, 0);
  hipLaunchKernelGGL((k_mfma<2,4,0>), dim3(N_TOK/64, 1), dim3(256), 0, stream,
                     cat, w1t, 256, b1, (const float*)nullptr, t1, (float*)nullptr, 128);
  hipLaunchKernelGGL(k_ln_bf16, dim3(N_TOK/4), dim3(256), 0, stream, t1, lag, lab, (unsigned*)h1, 64, 1);
  hipLaunchKernelGGL((k_mfma<2,4,0>), dim3(N_TOK/64, 1), dim3(256), 0, stream,
                     h1, w2t, 128, b2, (const float*)nullptr, out, (float*)nullptr, 128);
}

// Round 4
// 441.478 us; speedup vs baseline: 1.8194x; 1.1070x over previous
//
#include <hip/hip_runtime.h>
#include <hip/hip_bf16.h>
#include <math.h>

#define N_TOK 32768
#define LC 64
#define NCHUNK (N_TOK / LC)   // 512

typedef short short8 __attribute__((ext_vector_type(8)));   // 8 bf16 (4 VGPRs)
typedef float f32x4 __attribute__((ext_vector_type(4)));

__device__ __forceinline__ float siluf_(float v){ return v / (1.f + __expf(-v)); }
__device__ __forceinline__ float softplusf_(float v){ return v > 20.f ? v : log1pf(__expf(v)); }

__device__ __forceinline__ unsigned f2bfu(float f){
  __hip_bfloat16 h = __float2bfloat16(f);
  return (unsigned)*(unsigned short*)&h;
}

__device__ __forceinline__ float waveRed64(float v){
  #pragma unroll
  for (int m = 1; m < 64; m <<= 1) v += __shfl_xor(v, m);
  return v;
}

// ---------- W convert+transpose: wt[n*K+k] = bf16(w[k*N+n]) ----------
__global__ void k_wcvt(const float* __restrict__ w, __hip_bfloat16* __restrict__ wt, int K, int N){
  int e = blockIdx.x*256 + threadIdx.x;
  if (e >= K*N) return;
  int n = e / K, k = e % K;
  wt[e] = __float2bfloat16(w[k*N + n]);
}

// ---------- x_proj wt: [48][256], rows 40..47 zero ----------
__global__ void k_wcvt_xp(const float* __restrict__ w, __hip_bfloat16* __restrict__ wt){
  int e = blockIdx.x*256 + threadIdx.x;
  if (e >= 48*256) return;
  int n = e >> 8, k = e & 255;
  wt[e] = (n < 40) ? __float2bfloat16(w[k*40 + n]) : __float2bfloat16(0.f);
}

// ---------- K0: a0 = bf16(rmsnorm(feat)) ----------
__global__ void k_rms_bf16(const float* __restrict__ feat, const float* __restrict__ rmsw,
                           unsigned* __restrict__ a0u){
  int row = blockIdx.x*4 + (threadIdx.x>>6);
  int lane = threadIdx.x & 63;
  float2 f2 = ((const float2*)feat)[row*64 + lane];
  float ss = waveRed64(f2.x*f2.x + f2.y*f2.y);
  float is = rsqrtf(ss * (1.f/128.f) + 1e-5f);
  float2 w = ((const float2*)rmsw)[lane];
  a0u[row*64 + lane] = f2bfu(f2.x*is*w.x) | (f2bfu(f2.y*is*w.y) << 16);
}

// ---------- K1: gather + weighted-sum + LayerNorm -> cat[:,128:256] (bf16) ----------
__global__ void k_gather_ln(const float* __restrict__ feat, const int* __restrict__ ridx,
                            const float* __restrict__ gd, const float* __restrict__ g,
                            const float* __restrict__ b, unsigned* __restrict__ catu){
  int row = blockIdx.x*4 + (threadIdx.x>>6);
  int lane = threadIdx.x & 63;
  float ax=0.f, ay=0.f;
  #pragma unroll 4
  for (int k=0;k<16;k++){
    int idx = ridx[row*16+k];
    float w = gd[row*16+k];
    float2 f = ((const float2*)feat)[idx*64 + lane];
    ax += w*f.x; ay += w*f.y;
  }
  float m = waveRed64(ax+ay) * (1.f/128.f);
  float dx = ax-m, dy = ay-m;
  float var = waveRed64(dx*dx+dy*dy) * (1.f/128.f);
  float is = rsqrtf(var + 1e-5f);
  float2 gg = ((const float2*)g)[lane];
  float2 bb = ((const float2*)b)[lane];
  float ox = dx*is*gg.x + bb.x, oy = dy*is*gg.y + bb.y;
  catu[row*128 + 64 + lane] = f2bfu(ox) | (f2bfu(oy) << 16);
}

// ---------- MFMA GEMM: out[M,N] = A[M,K](bf16) @ Wt[N,K](bf16)^T ----------
template<int WM16, int WN16, int MODE>
__global__ __launch_bounds__(256) void k_mfma(const __hip_bfloat16* __restrict__ A,
      const __hip_bfloat16* __restrict__ Wt, int K,
      const float* __restrict__ bias, const float* __restrict__ resid,
      float* __restrict__ out0, float* __restrict__ out1, int ldout){
  int tid = threadIdx.x;
  int wave = tid>>6, lane = tid&63;
  int wm = wave>>1, wn = wave&1;
  int lane16 = lane&15, quad = lane>>4;
  int m_w = blockIdx.x*(2*WM16*16) + wm*(WM16*16);
  int n_w = blockIdx.y*(2*WN16*16) + wn*(WN16*16);
  f32x4 acc[WM16][WN16];
  #pragma unroll
  for (int i=0;i<WM16;i++)
    #pragma unroll
    for (int j=0;j<WN16;j++) acc[i][j] = (f32x4){0.f,0.f,0.f,0.f};
  const __hip_bfloat16* Ab = A  + (size_t)(m_w + lane16)*K + quad*8;
  const __hip_bfloat16* Bb = Wt + (size_t)(n_w + lane16)*K + quad*8;
  #pragma unroll 4
  for (int kk=0; kk<K; kk+=32){
    short8 a[WM16], b[WN16];
    #pragma unroll
    for (int i=0;i<WM16;i++) a[i] = *(const short8*)(Ab + (size_t)i*16*K + kk);
    #pragma unroll
    for (int j=0;j<WN16;j++) b[j] = *(const short8*)(Bb + (size_t)j*16*K + kk);
    #pragma unroll
    for (int i=0;i<WM16;i++)
      #pragma unroll
      for (int j=0;j<WN16;j++)
        acc[i][j] = __builtin_amdgcn_mfma_f32_16x16x32_bf16(a[i], b[j], acc[i][j], 0, 0, 0);
  }
  #pragma unroll
  for (int i=0;i<WM16;i++){
    #pragma unroll
    for (int j=0;j<WN16;j++){
      int n = n_w + j*16 + lane16;
      float bv = 0.f;
      if (MODE==0 && bias) bv = bias[n];
      #pragma unroll
      for (int r=0;r<4;r++){
        int m = m_w + i*16 + quad*4 + r;
        float v = acc[i][j][r] + bv;
        if (MODE==0){
          if (resid) v += resid[(size_t)m*ldout + n];
          out0[(size_t)m*ldout + n] = v;
        } else {
          if (n < 256) out0[(size_t)m*256 + n] = v;
          else         out1[(size_t)m*256 + (n-256)] = siluf_(v);
        }
      }
    }
  }
}

// ---------- xproj MFMA: dbc[M,48] = bxsb[M,256] @ xpwt[48,256]^T, split-store ----------
__global__ __launch_bounds__(256) void k_xproj_mfma(const __hip_bfloat16* __restrict__ A,
      const __hip_bfloat16* __restrict__ Wt,
      float* __restrict__ dt8, float* __restrict__ Bm, float* __restrict__ Cm){
  int tid = threadIdx.x;
  int wave = tid>>6, lane = tid&63;
  int lane16 = lane&15, quad = lane>>4;
  int m_w = blockIdx.x*64 + wave*16;
  f32x4 acc[3];
  #pragma unroll
  for (int j=0;j<3;j++) acc[j] = (f32x4){0.f,0.f,0.f,0.f};
  const __hip_bfloat16* Ab = A  + (size_t)(m_w + lane16)*256 + quad*8;
  const __hip_bfloat16* Bb = Wt + (size_t)lane16*256 + quad*8;
  #pragma unroll
  for (int kk=0; kk<256; kk+=32){
    short8 a = *(const short8*)(Ab + kk);
    short8 b0 = *(const short8*)(Bb + kk);
    short8 b1 = *(const short8*)(Bb + 16*256 + kk);
    short8 b2 = *(const short8*)(Bb + 32*256 + kk);
    acc[0] = __builtin_amdgcn_mfma_f32_16x16x32_bf16(a, b0, acc[0], 0, 0, 0);
    acc[1] = __builtin_amdgcn_mfma_f32_16x16x32_bf16(a, b1, acc[1], 0, 0, 0);
    acc[2] = __builtin_amdgcn_mfma_f32_16x16x32_bf16(a, b2, acc[2], 0, 0, 0);
  }
  #pragma unroll
  for (int j=0;j<3;j++){
    int n = j*16 + lane16;
    #pragma unroll
    for (int r=0;r<4;r++){
      int m = m_w + quad*4 + r;
      float v = acc[j][r];
      if (n < 8)       dt8[(size_t)m*8 + n] = v;
      else if (n < 24) Bm[(size_t)m*16 + (n-8)] = v;
      else if (n < 40) Cm[(size_t)m*16 + (n-24)] = v;
    }
  }
}

// ---------- K3: causal depthwise conv (D_CONV=4) + silu -> bxs (f32) + bxsb (bf16) ----------
__global__ void __launch_bounds__(256) k_conv(const float* __restrict__ bx,
      const float* __restrict__ cw, const float* __restrict__ cb,
      float* __restrict__ bxs, __hip_bfloat16* __restrict__ bxsb){
  __shared__ float Xs[67][256];
  int r0 = blockIdx.x*64;
  int d = threadIdx.x;
  for (int i=0;i<67;i++){
    int gr = r0 - 3 + i;
    Xs[i][d] = (gr >= 0) ? bx[gr*256 + d] : 0.f;
  }
  __syncthreads();
  float w0=cw[d*4], w1=cw[d*4+1], w2=cw[d*4+2], w3=cw[d*4+3], bb=cb[d];
  float a0=Xs[0][d], a1=Xs[1][d], a2=Xs[2][d];
  for (int t=0;t<64;t++){
    float a3 = Xs[t+3][d];
    float xc = bb + w0*a0 + w1*a1 + w2*a2 + w3*a3;
    float sv = siluf_(xc);
    bxs[(r0+t)*256 + d] = sv;
    bxsb[(size_t)(r0+t)*256 + d] = __float2bfloat16(sv);
    a0=a1; a1=a2; a2=a3;
  }
}

// ---------- K4b: delta = softplus(dt8 @ dt_proj_w + dt_proj_b) ----------
__global__ void __launch_bounds__(256) k_delta(const float* __restrict__ dt8,
      const float* __restrict__ dtw, const float* __restrict__ dtb, float* __restrict__ delta){
  __shared__ float T8[64][8];
  __shared__ float Wd[8][256];
  int r0 = blockIdx.x*64;
  int tid = threadIdx.x;
  for (int e=tid; e<512; e+=256){ int r=e>>3, c=e&7; T8[r][c] = dt8[(r0+r)*8 + c]; }
  for (int e=tid; e<2048; e+=256){ int j=e>>8, d=e&255; Wd[j][d] = dtw[j*256 + d]; }
  __syncthreads();
  int d = tid;
  float bb = dtb[d];
  for (int r=0;r<64;r++){
    float acc = bb;
    #pragma unroll
    for (int j=0;j<8;j++) acc += T8[r][j]*Wd[j][d];
    delta[(r0+r)*256 + d] = softplusf_(acc);
  }
}

// ---------- K5: scan pass 1 — one wave per (chunk, 64-channel group), no LDS ----------
__global__ __launch_bounds__(64) void k_scan1(const float* __restrict__ delta,
      const float* __restrict__ bxs, const float* __restrict__ Bm,
      const float* __restrict__ A_log, float* __restrict__ Pc, float* __restrict__ Hc){
  int g = blockIdx.x;
  int d = blockIdx.y*64 + threadIdx.x;
  int t0 = g*LC;
  float aS[16];
  #pragma unroll
  for (int s=0;s<16;s++) aS[s] = -__expf(A_log[d*16+s]);
  float h[16] = {};
  float dsum = 0.f;
  #pragma unroll 2
  for (int t=0;t<LC;t++){
    float dv = delta[(size_t)(t0+t)*256 + d];
    float xv = bxs[(size_t)(t0+t)*256 + d];
    const float4* Bp = (const float4*)(Bm + (size_t)(t0+t)*16);
    float4 b0=Bp[0], b1=Bp[1], b2=Bp[2], b3=Bp[3];
    float bl[16] = {b0.x,b0.y,b0.z,b0.w, b1.x,b1.y,b1.z,b1.w,
                    b2.x,b2.y,b2.z,b2.w, b3.x,b3.y,b3.z,b3.w};
    dsum += dv;
    float dx_ = dv*xv;
    #pragma unroll
    for (int s=0;s<16;s++) h[s] = __expf(dv*aS[s])*h[s] + dx_*bl[s];
  }
  size_t base = (size_t)g*4096 + (size_t)d*16;
  float4* Pd = (float4*)(Pc + base);
  float4* Hd = (float4*)(Hc + base);
  #pragma unroll
  for (int q=0;q<4;q++){
    Pd[q] = make_float4(__expf(dsum*aS[q*4]), __expf(dsum*aS[q*4+1]),
                        __expf(dsum*aS[q*4+2]), __expf(dsum*aS[q*4+3]));
    Hd[q] = make_float4(h[q*4], h[q*4+1], h[q*4+2], h[q*4+3]);
  }
}

// ---------- K6: carry scan across chunks (in place: HC holds H on entry, Cr on exit) ----------
__global__ __launch_bounds__(64) void k_carry(const float* __restrict__ Pc, float* HC){
  int ch = blockIdx.x*64 + threadIdx.x;
  float c = 0.f;
  #pragma unroll 8
  for (int g=0; g<NCHUNK; g++){
    size_t a = (size_t)g*4096 + ch;
    float p  = Pc[a];
    float hh = HC[a];
    HC[a] = c;
    c = p*c + hh;
  }
}

// ---------- K7: scan pass 2 — seeded local scan, final gated y (bf16), no LDS ----------
__global__ __launch_bounds__(64) void k_scan2(const float* __restrict__ delta,
      const float* __restrict__ bxs, const float* __restrict__ Bm, const float* __restrict__ Cm,
      const float* __restrict__ bsz, const float* __restrict__ A_log,
      const float* __restrict__ Dp, const float* __restrict__ Cr,
      __hip_bfloat16* __restrict__ yb){
  int g = blockIdx.x;
  int d = blockIdx.y*64 + threadIdx.x;
  int t0 = g*LC;
  float aS[16];
  #pragma unroll
  for (int s=0;s<16;s++) aS[s] = -__expf(A_log[d*16+s]);
  float h[16];
  {
    const float4* hc = (const float4*)(Cr + (size_t)g*4096 + (size_t)d*16);
    #pragma unroll
    for (int q=0;q<4;q++){
      float4 v = hc[q];
      h[q*4]=v.x; h[q*4+1]=v.y; h[q*4+2]=v.z; h[q*4+3]=v.w;
    }
  }
  float dpar = Dp[d];
  #pragma unroll 2
  for (int t=0;t<LC;t++){
    float dv = delta[(size_t)(t0+t)*256 + d];
    float xv = bxs[(size_t)(t0+t)*256 + d];
    float zv = bsz[(size_t)(t0+t)*256 + d];
    const float4* Bp = (const float4*)(Bm + (size_t)(t0+t)*16);
    const float4* Cp = (const float4*)(Cm + (size_t)(t0+t)*16);
    float4 b0=Bp[0], b1=Bp[1], b2=Bp[2], b3=Bp[3];
    float4 c0=Cp[0], c1=Cp[1], c2=Cp[2], c3=Cp[3];
    float bl[16] = {b0.x,b0.y,b0.z,b0.w, b1.x,b1.y,b1.z,b1.w,
                    b2.x,b2.y,b2.z,b2.w, b3.x,b3.y,b3.z,b3.w};
    float cl[16] = {c0.x,c0.y,c0.z,c0.w, c1.x,c1.y,c1.z,c1.w,
                    c2.x,c2.y,c2.z,c2.w, c3.x,c3.y,c3.z,c3.w};
    float dx_ = dv*xv;
    float yv = 0.f;
    #pragma unroll
    for (int s=0;s<16;s++){
      h[s] = __expf(dv*aS[s])*h[s] + dx_*bl[s];
      yv += h[s]*cl[s];
    }
    yb[(size_t)(t0+t)*256 + d] = __float2bfloat16((yv + dpar*xv)*zv);
  }
}

// ---------- LayerNorm (fp32 in) -> bf16 out, optional relu ----------
__global__ void k_ln_bf16(const float* __restrict__ in, const float* __restrict__ g,
                          const float* __restrict__ b, unsigned* __restrict__ outu,
                          int ldh_u, int dorelu){
  int row = blockIdx.x*4 + (threadIdx.x>>6);
  int lane = threadIdx.x & 63;
  float2 v = ((const float2*)in)[row*64 + lane];
  float m = waveRed64(v.x+v.y) * (1.f/128.f);
  float dx = v.x - m, dy = v.y - m;
  float var = waveRed64(dx*dx + dy*dy) * (1.f/128.f);
  float is = rsqrtf(var + 1e-5f);
  float2 gg = ((const float2*)g)[lane];
  float2 bb = ((const float2*)b)[lane];
  float ox = dx*is*gg.x + bb.x;
  float oy = dy*is*gg.y + bb.y;
  if (dorelu){ ox = fmaxf(ox, 0.f); oy = fmaxf(oy, 0.f); }
  outu[row*ldh_u + lane] = f2bfu(ox) | (f2bfu(oy) << 16);
}

extern "C" void kernel_launch(void* const* d_in, const int* in_sizes, int n_in,
                              void* d_out, int out_size, void* d_ws, size_t ws_size,
                              hipStream_t stream){
  const float* feat = (const float*)d_in[0];
  const int*   ridx = (const int*)d_in[2];
  const float* gd   = (const float*)d_in[3];
  const float* ipw  = (const float*)d_in[5];
  const float* cw   = (const float*)d_in[6];
  const float* cb   = (const float*)d_in[7];
  const float* xpw  = (const float*)d_in[8];
  const float* dtw  = (const float*)d_in[9];
  const float* dtb  = (const float*)d_in[10];
  const float* alog = (const float*)d_in[11];
  const float* dpar = (const float*)d_in[12];
  const float* opw  = (const float*)d_in[13];
  const float* rmsw = (const float*)d_in[14];
  const float* lng  = (const float*)d_in[15];
  const float* lnb  = (const float*)d_in[16];
  const float* w1   = (const float*)d_in[17];
  const float* b1   = (const float*)d_in[18];
  const float* lag  = (const float*)d_in[19];
  const float* lab  = (const float*)d_in[20];
  const float* w2   = (const float*)d_in[21];
  const float* b2   = (const float*)d_in[22];
  float* out = (float*)d_out;

  float* ws    = (float*)d_ws;
  float* bx    = ws;                       // N*256 f32: pre-conv x; then Pc|HcCr|yb
  float* bsz   = bx   + (size_t)N_TOK*256; // N*256 f32 silu(z); later h1 (bf16)
  float* bxs   = bsz  + (size_t)N_TOK*256; // N*256 f32 silu(conv(x)); a0 (bf16) lives here pre-conv
  float* delta = bxs  + (size_t)N_TOK*256; // N*256 f32; later t1 (f32 N*128)
  float* dt8   = delta + (size_t)N_TOK*256;// N*8
  float* Bm    = dt8  + (size_t)N_TOK*8;   // N*16
  float* Cm    = Bm   + (size_t)N_TOK*16;  // N*16
  __hip_bfloat16* cat  = (__hip_bfloat16*)(Cm + (size_t)N_TOK*16);  // N*256 bf16
  __hip_bfloat16* bxsb = cat  + (size_t)N_TOK*256;                  // N*256 bf16
  __hip_bfloat16* ipwt = bxsb + (size_t)N_TOK*256;                  // 512*128
  __hip_bfloat16* opwt = ipwt + 512*128;
  __hip_bfloat16* w1t  = opwt + 128*256;
  __hip_bfloat16* w2t  = w1t  + 128*256;
  __hip_bfloat16* xpwt = w2t  + 128*128;                            // 48*256
  // aliases in bx region (bx dead after conv):
  float* Pc  = bx;                                   // NCHUNK*4096 = 8 MB
  float* HcCr= bx + (size_t)NCHUNK*4096;             // 8 MB (H, then Cr in-place)
  __hip_bfloat16* yb = (__hip_bfloat16*)(bx + 2*(size_t)NCHUNK*4096); // N*256 bf16 = 16 MB
  // other aliases:
  __hip_bfloat16* a0 = (__hip_bfloat16*)bxs;   // N*128 bf16 (dead once conv writes bxs)
  float*          t1 = delta;                  // N*128 f32 (delta dead after scan2)
  __hip_bfloat16* h1 = (__hip_bfloat16*)bsz;   // N*128 bf16 (bsz dead after scan2)

  hipLaunchKernelGGL(k_wcvt, dim3((128*512+255)/256), dim3(256), 0, stream, ipw, ipwt, 128, 512);
  hipLaunchKernelGGL(k_wcvt, dim3((256*128+255)/256), dim3(256), 0, stream, opw, opwt, 256, 128);
  hipLaunchKernelGGL(k_wcvt, dim3((256*128+255)/256), dim3(256), 0, stream, w1, w1t, 256, 128);
  hipLaunchKernelGGL(k_wcvt, dim3((128*128+255)/256), dim3(256), 0, stream, w2, w2t, 128, 128);
  hipLaunchKernelGGL(k_wcvt_xp, dim3((48*256+255)/256), dim3(256), 0, stream, xpw, xpwt);

  hipLaunchKernelGGL(k_rms_bf16,  dim3(N_TOK/4), dim3(256), 0, stream, feat, rmsw, (unsigned*)a0);
  hipLaunchKernelGGL(k_gather_ln, dim3(N_TOK/4), dim3(256), 0, stream, feat, ridx, gd, lng, lnb, (unsigned*)cat);
  hipLaunchKernelGGL((k_mfma<4,4,1>), dim3(N_TOK/128, 4), dim3(256), 0, stream,
                     a0, ipwt, 128, (const float*)nullptr, (const float*)nullptr, bx, bsz, 256);
  hipLaunchKernelGGL(k_conv,  dim3(N_TOK/64), dim3(256), 0, stream, bx, cw, cb, bxs, bxsb);
  hipLaunchKernelGGL(k_xproj_mfma, dim3(N_TOK/64), dim3(256), 0, stream, bxsb, xpwt, dt8, Bm, Cm);
  hipLaunchKernelGGL(k_delta, dim3(N_TOK/64), dim3(256), 0, stream, dt8, dtw, dtb, delta);
  hipLaunchKernelGGL(k_scan1, dim3(NCHUNK, 4), dim3(64), 0, stream, delta, bxs, Bm, alog, Pc, HcCr);
  hipLaunchKernelGGL(k_carry, dim3(64), dim3(64), 0, stream, Pc, HcCr);
  hipLaunchKernelGGL(k_scan2, dim3(NCHUNK, 4), dim3(64), 0, stream, delta, bxs, Bm, Cm, bsz, alog, dpar, HcCr, yb);
  hipLaunchKernelGGL((k_mfma<2,4,0>), dim3(N_TOK/64, 1), dim3(256), 0, stream,
                     yb, opwt, 256, (const float*)nullptr, feat, t1, (float*)nullptr, 128);
  hipLaunchKernelGGL(k_ln_bf16, dim3(N_TOK/4), dim3(256), 0, stream, t1, lng, lnb, (unsigned*)cat, 128, 0);
  hipLaunchKernelGGL((k_mfma<2,4,0>), dim3(N_TOK/64, 1), dim3(256), 0, stream,
                     cat, w1t, 256, b1, (const float*)nullptr, t1, (float*)nullptr, 128);
  hipLaunchKernelGGL(k_ln_bf16, dim3(N_TOK/4), dim3(256), 0, stream, t1, lag, lab, (unsigned*)h1, 64, 1);
  hipLaunchKernelGGL((k_mfma<2,4,0>), dim3(N_TOK/64, 1), dim3(256), 0, stream,
                     h1, w2t, 128, b2, (const float*)nullptr, out, (float*)nullptr, 128);
}

// Round 5
// 422.071 us; speedup vs baseline: 1.9031x; 1.0460x over previous
//
#include <hip/hip_runtime.h>
#include <hip/hip_bf16.h>
#include <math.h>

#define N_TOK 32768
#define LC 64
#define NCHUNK (N_TOK / LC)   // 512

typedef short short8 __attribute__((ext_vector_type(8)));   // 8 bf16 (4 VGPRs)
typedef float f32x4 __attribute__((ext_vector_type(4)));

__device__ __forceinline__ float siluf_(float v){ return v / (1.f + __expf(-v)); }
__device__ __forceinline__ float softplusf_(float v){ return v > 20.f ? v : log1pf(__expf(v)); }

__device__ __forceinline__ unsigned f2bfu(float f){
  __hip_bfloat16 h = __float2bfloat16(f);
  return (unsigned)*(unsigned short*)&h;
}

__device__ __forceinline__ float waveRed64(float v){
  #pragma unroll
  for (int m = 1; m < 64; m <<= 1) v += __shfl_xor(v, m);
  return v;
}

// ---------- all weight converts in one launch ----------
// segs: ipwt 65536 | opwt 32768 | w1t 32768 | w2t 16384 | xpwt 12288  (cum 159744)
__global__ void k_wcvt_all(const float* __restrict__ ipw, const float* __restrict__ opw,
                           const float* __restrict__ w1, const float* __restrict__ w2,
                           const float* __restrict__ xpw,
                           __hip_bfloat16* __restrict__ ipwt, __hip_bfloat16* __restrict__ opwt,
                           __hip_bfloat16* __restrict__ w1t, __hip_bfloat16* __restrict__ w2t,
                           __hip_bfloat16* __restrict__ xpwt){
  int e = blockIdx.x*256 + threadIdx.x;
  if (e < 65536){ int n=e>>7, k=e&127; ipwt[e]=__float2bfloat16(ipw[k*512+n]); }
  else if (e < 98304){ int f=e-65536; int n=f>>8, k=f&255; opwt[f]=__float2bfloat16(opw[k*128+n]); }
  else if (e < 131072){ int f=e-98304; int n=f>>8, k=f&255; w1t[f]=__float2bfloat16(w1[k*128+n]); }
  else if (e < 147456){ int f=e-131072; int n=f>>7, k=f&127; w2t[f]=__float2bfloat16(w2[k*128+n]); }
  else if (e < 159744){ int f=e-147456; int n=f>>8, k=f&255;
                        xpwt[f]=(n<40)?__float2bfloat16(xpw[k*40+n]):__float2bfloat16(0.f); }
}

// ---------- K1: fused rmsnorm(feat)->a0 AND gather+LN->cat[:,128:256] ----------
__global__ void k_gat_rms(const float* __restrict__ feat, const int* __restrict__ ridx,
                          const float* __restrict__ gd, const float* __restrict__ g,
                          const float* __restrict__ b, const float* __restrict__ rmsw,
                          unsigned* __restrict__ catu, unsigned* __restrict__ a0u){
  int row = blockIdx.x*4 + (threadIdx.x>>6);
  int lane = threadIdx.x & 63;
  // rms part
  float2 f2 = ((const float2*)feat)[row*64 + lane];
  float ss = waveRed64(f2.x*f2.x + f2.y*f2.y);
  float is0 = rsqrtf(ss * (1.f/128.f) + 1e-5f);
  float2 w = ((const float2*)rmsw)[lane];
  a0u[row*64 + lane] = f2bfu(f2.x*is0*w.x) | (f2bfu(f2.y*is0*w.y) << 16);
  // gather + LN part
  float ax=0.f, ay=0.f;
  #pragma unroll 4
  for (int k=0;k<16;k++){
    int idx = ridx[row*16+k];
    float ww = gd[row*16+k];
    float2 f = ((const float2*)feat)[idx*64 + lane];
    ax += ww*f.x; ay += ww*f.y;
  }
  float m = waveRed64(ax+ay) * (1.f/128.f);
  float dx = ax-m, dy = ay-m;
  float var = waveRed64(dx*dx+dy*dy) * (1.f/128.f);
  float is = rsqrtf(var + 1e-5f);
  float2 gg = ((const float2*)g)[lane];
  float2 bb = ((const float2*)b)[lane];
  float ox = dx*is*gg.x + bb.x, oy = dy*is*gg.y + bb.y;
  catu[row*128 + 64 + lane] = f2bfu(ox) | (f2bfu(oy) << 16);
}

// ---------- MFMA GEMM: out[M,N] = A[M,K](bf16) @ Wt[N,K](bf16)^T ----------
template<int WM16, int WN16, int MODE>
__global__ __launch_bounds__(256) void k_mfma(const __hip_bfloat16* __restrict__ A,
      const __hip_bfloat16* __restrict__ Wt, int K,
      const float* __restrict__ bias, const float* __restrict__ resid,
      float* __restrict__ out0, float* __restrict__ out1, int ldout){
  int tid = threadIdx.x;
  int wave = tid>>6, lane = tid&63;
  int wm = wave>>1, wn = wave&1;
  int lane16 = lane&15, quad = lane>>4;
  int m_w = blockIdx.x*(2*WM16*16) + wm*(WM16*16);
  int n_w = blockIdx.y*(2*WN16*16) + wn*(WN16*16);
  f32x4 acc[WM16][WN16];
  #pragma unroll
  for (int i=0;i<WM16;i++)
    #pragma unroll
    for (int j=0;j<WN16;j++) acc[i][j] = (f32x4){0.f,0.f,0.f,0.f};
  const __hip_bfloat16* Ab = A  + (size_t)(m_w + lane16)*K + quad*8;
  const __hip_bfloat16* Bb = Wt + (size_t)(n_w + lane16)*K + quad*8;
  #pragma unroll 4
  for (int kk=0; kk<K; kk+=32){
    short8 a[WM16], b[WN16];
    #pragma unroll
    for (int i=0;i<WM16;i++) a[i] = *(const short8*)(Ab + (size_t)i*16*K + kk);
    #pragma unroll
    for (int j=0;j<WN16;j++) b[j] = *(const short8*)(Bb + (size_t)j*16*K + kk);
    #pragma unroll
    for (int i=0;i<WM16;i++)
      #pragma unroll
      for (int j=0;j<WN16;j++)
        acc[i][j] = __builtin_amdgcn_mfma_f32_16x16x32_bf16(a[i], b[j], acc[i][j], 0, 0, 0);
  }
  #pragma unroll
  for (int i=0;i<WM16;i++){
    #pragma unroll
    for (int j=0;j<WN16;j++){
      int n = n_w + j*16 + lane16;
      float bv = 0.f;
      if (MODE==0 && bias) bv = bias[n];
      #pragma unroll
      for (int r=0;r<4;r++){
        int m = m_w + i*16 + quad*4 + r;
        float v = acc[i][j][r] + bv;
        if (MODE==0){
          if (resid) v += resid[(size_t)m*ldout + n];
          out0[(size_t)m*ldout + n] = v;
        } else {
          if (n < 256) out0[(size_t)m*256 + n] = v;
          else         out1[(size_t)m*256 + (n-256)] = siluf_(v);
        }
      }
    }
  }
}

// ---------- xproj MFMA: dbc[M,48] = bxsb[M,256] @ xpwt[48,256]^T, split-store ----------
__global__ __launch_bounds__(256) void k_xproj_mfma(const __hip_bfloat16* __restrict__ A,
      const __hip_bfloat16* __restrict__ Wt,
      float* __restrict__ dt8, float* __restrict__ Bm, float* __restrict__ Cm){
  int tid = threadIdx.x;
  int wave = tid>>6, lane = tid&63;
  int lane16 = lane&15, quad = lane>>4;
  int m_w = blockIdx.x*64 + wave*16;
  f32x4 acc[3];
  #pragma unroll
  for (int j=0;j<3;j++) acc[j] = (f32x4){0.f,0.f,0.f,0.f};
  const __hip_bfloat16* Ab = A  + (size_t)(m_w + lane16)*256 + quad*8;
  const __hip_bfloat16* Bb = Wt + (size_t)lane16*256 + quad*8;
  #pragma unroll
  for (int kk=0; kk<256; kk+=32){
    short8 a = *(const short8*)(Ab + kk);
    short8 b0 = *(const short8*)(Bb + kk);
    short8 b1 = *(const short8*)(Bb + 16*256 + kk);
    short8 b2 = *(const short8*)(Bb + 32*256 + kk);
    acc[0] = __builtin_amdgcn_mfma_f32_16x16x32_bf16(a, b0, acc[0], 0, 0, 0);
    acc[1] = __builtin_amdgcn_mfma_f32_16x16x32_bf16(a, b1, acc[1], 0, 0, 0);
    acc[2] = __builtin_amdgcn_mfma_f32_16x16x32_bf16(a, b2, acc[2], 0, 0, 0);
  }
  #pragma unroll
  for (int j=0;j<3;j++){
    int n = j*16 + lane16;
    #pragma unroll
    for (int r=0;r<4;r++){
      int m = m_w + quad*4 + r;
      float v = acc[j][r];
      if (n < 8)       dt8[(size_t)m*8 + n] = v;
      else if (n < 24) Bm[(size_t)m*16 + (n-8)] = v;
      else if (n < 40) Cm[(size_t)m*16 + (n-24)] = v;
    }
  }
}

// ---------- K3: causal depthwise conv + silu, no LDS, 32-t blocks ----------
__global__ void __launch_bounds__(256) k_conv(const float* __restrict__ bx,
      const float* __restrict__ cw, const float* __restrict__ cb,
      float* __restrict__ bxs, __hip_bfloat16* __restrict__ bxsb){
  int r0 = blockIdx.x*32;
  int d = threadIdx.x;
  float w0=cw[d*4], w1=cw[d*4+1], w2=cw[d*4+2], w3=cw[d*4+3], bb=cb[d];
  float a0 = (r0 >= 3) ? bx[(size_t)(r0-3)*256 + d] : 0.f;
  float a1 = (r0 >= 2) ? bx[(size_t)(r0-2)*256 + d] : 0.f;
  float a2 = (r0 >= 1) ? bx[(size_t)(r0-1)*256 + d] : 0.f;
  #pragma unroll 4
  for (int t=0;t<32;t++){
    float a3 = bx[(size_t)(r0+t)*256 + d];
    float xc = bb + w0*a0 + w1*a1 + w2*a2 + w3*a3;
    float sv = siluf_(xc);
    bxs[(size_t)(r0+t)*256 + d] = sv;
    bxsb[(size_t)(r0+t)*256 + d] = __float2bfloat16(sv);
    a0=a1; a1=a2; a2=a3;
  }
}

// ---------- K4b: delta = softplus(dt8 @ dt_proj_w + dt_proj_b) ----------
__global__ void __launch_bounds__(256) k_delta(const float* __restrict__ dt8,
      const float* __restrict__ dtw, const float* __restrict__ dtb, float* __restrict__ delta){
  __shared__ float T8[64][8];
  __shared__ float Wd[8][256];
  int r0 = blockIdx.x*64;
  int tid = threadIdx.x;
  for (int e=tid; e<512; e+=256){ int r=e>>3, c=e&7; T8[r][c] = dt8[(r0+r)*8 + c]; }
  for (int e=tid; e<2048; e+=256){ int j=e>>8, d=e&255; Wd[j][d] = dtw[j*256 + d]; }
  __syncthreads();
  int d = tid;
  float bb = dtb[d];
  for (int r=0;r<64;r++){
    float acc = bb;
    #pragma unroll
    for (int j=0;j<8;j++) acc += T8[r][j]*Wd[j][d];
    delta[(r0+r)*256 + d] = softplusf_(acc);
  }
}

// ---------- K5: scan pass 1 — 2 threads/channel (8 states each), no LDS ----------
__global__ __launch_bounds__(64) void k_scan1(const float* __restrict__ delta,
      const float* __restrict__ bxs, const float* __restrict__ Bm,
      const float* __restrict__ A_log, float* __restrict__ Pc, float* __restrict__ Hc){
  int g = blockIdx.x;
  int ch = threadIdx.x & 31, half = threadIdx.x >> 5;
  int d = blockIdx.y*32 + ch;
  int t0 = g*LC;
  float aS[8];
  #pragma unroll
  for (int s=0;s<8;s++) aS[s] = -__expf(A_log[d*16 + half*8 + s]);
  float h[8] = {};
  float dsum = 0.f;
  #pragma unroll 2
  for (int t=0;t<LC;t++){
    float dv = delta[(size_t)(t0+t)*256 + d];
    float xv = bxs[(size_t)(t0+t)*256 + d];
    const float4* Bp = (const float4*)(Bm + (size_t)(t0+t)*16 + half*8);
    float4 b0=Bp[0], b1=Bp[1];
    float bl[8] = {b0.x,b0.y,b0.z,b0.w, b1.x,b1.y,b1.z,b1.w};
    dsum += dv;
    float dx_ = dv*xv;
    #pragma unroll
    for (int s=0;s<8;s++) h[s] = __expf(dv*aS[s])*h[s] + dx_*bl[s];
  }
  size_t base = (size_t)g*4096 + (size_t)d*16 + half*8;
  float4* Pd = (float4*)(Pc + base);
  float4* Hd = (float4*)(Hc + base);
  Pd[0] = make_float4(__expf(dsum*aS[0]), __expf(dsum*aS[1]), __expf(dsum*aS[2]), __expf(dsum*aS[3]));
  Pd[1] = make_float4(__expf(dsum*aS[4]), __expf(dsum*aS[5]), __expf(dsum*aS[6]), __expf(dsum*aS[7]));
  Hd[0] = make_float4(h[0],h[1],h[2],h[3]);
  Hd[1] = make_float4(h[4],h[5],h[6],h[7]);
}

// ---------- K6: carry scan across chunks (in place: HC holds H on entry, Cr on exit) ----------
__global__ __launch_bounds__(64) void k_carry(const float* __restrict__ Pc, float* HC){
  int ch = blockIdx.x*64 + threadIdx.x;
  float c = 0.f;
  #pragma unroll 8
  for (int g=0; g<NCHUNK; g++){
    size_t a = (size_t)g*4096 + ch;
    float p  = Pc[a];
    float hh = HC[a];
    HC[a] = c;
    c = p*c + hh;
  }
}

// ---------- K7: scan pass 2 — seeded local scan, final gated y (bf16) ----------
__global__ __launch_bounds__(64) void k_scan2(const float* __restrict__ delta,
      const float* __restrict__ bxs, const float* __restrict__ Bm, const float* __restrict__ Cm,
      const float* __restrict__ bsz, const float* __restrict__ A_log,
      const float* __restrict__ Dp, const float* __restrict__ Cr,
      __hip_bfloat16* __restrict__ yb){
  int g = blockIdx.x;
  int ch = threadIdx.x & 31, half = threadIdx.x >> 5;
  int d = blockIdx.y*32 + ch;
  int t0 = g*LC;
  float aS[8];
  #pragma unroll
  for (int s=0;s<8;s++) aS[s] = -__expf(A_log[d*16 + half*8 + s]);
  float h[8];
  {
    const float4* hc = (const float4*)(Cr + (size_t)g*4096 + (size_t)d*16 + half*8);
    float4 v0 = hc[0], v1 = hc[1];
    h[0]=v0.x; h[1]=v0.y; h[2]=v0.z; h[3]=v0.w;
    h[4]=v1.x; h[5]=v1.y; h[6]=v1.z; h[7]=v1.w;
  }
  float dpar = Dp[d];
  #pragma unroll 2
  for (int t=0;t<LC;t++){
    float dv = delta[(size_t)(t0+t)*256 + d];
    float xv = bxs[(size_t)(t0+t)*256 + d];
    float zv = bsz[(size_t)(t0+t)*256 + d];
    const float4* Bp = (const float4*)(Bm + (size_t)(t0+t)*16 + half*8);
    const float4* Cp = (const float4*)(Cm + (size_t)(t0+t)*16 + half*8);
    float4 b0=Bp[0], b1=Bp[1];
    float4 c0=Cp[0], c1=Cp[1];
    float bl[8] = {b0.x,b0.y,b0.z,b0.w, b1.x,b1.y,b1.z,b1.w};
    float cl[8] = {c0.x,c0.y,c0.z,c0.w, c1.x,c1.y,c1.z,c1.w};
    float dx_ = dv*xv;
    float yv = 0.f;
    #pragma unroll
    for (int s=0;s<8;s++){
      h[s] = __expf(dv*aS[s])*h[s] + dx_*bl[s];
      yv += h[s]*cl[s];
    }
    yv += __shfl_xor(yv, 32);
    if (half == 0)
      yb[(size_t)(t0+t)*256 + d] = __float2bfloat16((yv + dpar*xv)*zv);
  }
}

// ---------- LayerNorm (fp32 in) -> bf16 out, optional relu ----------
__global__ void k_ln_bf16(const float* __restrict__ in, const float* __restrict__ g,
                          const float* __restrict__ b, unsigned* __restrict__ outu,
                          int ldh_u, int dorelu){
  int row = blockIdx.x*4 + (threadIdx.x>>6);
  int lane = threadIdx.x & 63;
  float2 v = ((const float2*)in)[row*64 + lane];
  float m = waveRed64(v.x+v.y) * (1.f/128.f);
  float dx = v.x - m, dy = v.y - m;
  float var = waveRed64(dx*dx + dy*dy) * (1.f/128.f);
  float is = rsqrtf(var + 1e-5f);
  float2 gg = ((const float2*)g)[lane];
  float2 bb = ((const float2*)b)[lane];
  float ox = dx*is*gg.x + bb.x;
  float oy = dy*is*gg.y + bb.y;
  if (dorelu){ ox = fmaxf(ox, 0.f); oy = fmaxf(oy, 0.f); }
  outu[row*ldh_u + lane] = f2bfu(ox) | (f2bfu(oy) << 16);
}

extern "C" void kernel_launch(void* const* d_in, const int* in_sizes, int n_in,
                              void* d_out, int out_size, void* d_ws, size_t ws_size,
                              hipStream_t stream){
  const float* feat = (const float*)d_in[0];
  const int*   ridx = (const int*)d_in[2];
  const float* gd   = (const float*)d_in[3];
  const float* ipw  = (const float*)d_in[5];
  const float* cw   = (const float*)d_in[6];
  const float* cb   = (const float*)d_in[7];
  const float* xpw  = (const float*)d_in[8];
  const float* dtw  = (const float*)d_in[9];
  const float* dtb  = (const float*)d_in[10];
  const float* alog = (const float*)d_in[11];
  const float* dpar = (const float*)d_in[12];
  const float* opw  = (const float*)d_in[13];
  const float* rmsw = (const float*)d_in[14];
  const float* lng  = (const float*)d_in[15];
  const float* lnb  = (const float*)d_in[16];
  const float* w1   = (const float*)d_in[17];
  const float* b1   = (const float*)d_in[18];
  const float* lag  = (const float*)d_in[19];
  const float* lab  = (const float*)d_in[20];
  const float* w2   = (const float*)d_in[21];
  const float* b2   = (const float*)d_in[22];
  float* out = (float*)d_out;

  float* ws    = (float*)d_ws;
  float* bx    = ws;                       // N*256 f32: pre-conv x; then Pc|HcCr|yb
  float* bsz   = bx   + (size_t)N_TOK*256; // N*256 f32 silu(z); later h1 (bf16)
  float* bxs   = bsz  + (size_t)N_TOK*256; // N*256 f32 silu(conv(x)); a0 (bf16) pre-conv
  float* delta = bxs  + (size_t)N_TOK*256; // N*256 f32; later t1 (f32 N*128)
  float* dt8   = delta + (size_t)N_TOK*256;// N*8
  float* Bm    = dt8  + (size_t)N_TOK*8;   // N*16
  float* Cm    = Bm   + (size_t)N_TOK*16;  // N*16
  __hip_bfloat16* cat  = (__hip_bfloat16*)(Cm + (size_t)N_TOK*16);  // N*256 bf16
  __hip_bfloat16* bxsb = cat  + (size_t)N_TOK*256;                  // N*256 bf16
  __hip_bfloat16* ipwt = bxsb + (size_t)N_TOK*256;                  // 512*128
  __hip_bfloat16* opwt = ipwt + 512*128;
  __hip_bfloat16* w1t  = opwt + 128*256;
  __hip_bfloat16* w2t  = w1t  + 128*256;
  __hip_bfloat16* xpwt = w2t  + 128*128;                            // 48*256
  // aliases in bx region (bx dead after conv):
  float* Pc  = bx;                                   // NCHUNK*4096 = 8 MB
  float* HcCr= bx + (size_t)NCHUNK*4096;             // 8 MB (H, then Cr in-place)
  __hip_bfloat16* yb = (__hip_bfloat16*)(bx + 2*(size_t)NCHUNK*4096); // N*256 bf16
  // other aliases:
  __hip_bfloat16* a0 = (__hip_bfloat16*)bxs;   // N*128 bf16 (dead once conv writes bxs)
  float*          t1 = delta;                  // N*128 f32 (delta dead after scan2)
  __hip_bfloat16* h1 = (__hip_bfloat16*)bsz;   // N*128 bf16 (bsz dead after scan2)

  hipLaunchKernelGGL(k_wcvt_all, dim3(624), dim3(256), 0, stream,
                     ipw, opw, w1, w2, xpw, ipwt, opwt, w1t, w2t, xpwt);
  hipLaunchKernelGGL(k_gat_rms,  dim3(N_TOK/4), dim3(256), 0, stream,
                     feat, ridx, gd, lng, lnb, rmsw, (unsigned*)cat, (unsigned*)a0);
  hipLaunchKernelGGL((k_mfma<4,4,1>), dim3(N_TOK/128, 4), dim3(256), 0, stream,
                     a0, ipwt, 128, (const float*)nullptr, (const float*)nullptr, bx, bsz, 256);
  hipLaunchKernelGGL(k_conv,  dim3(N_TOK/32), dim3(256), 0, stream, bx, cw, cb, bxs, bxsb);
  hipLaunchKernelGGL(k_xproj_mfma, dim3(N_TOK/64), dim3(256), 0, stream, bxsb, xpwt, dt8, Bm, Cm);
  hipLaunchKernelGGL(k_delta, dim3(N_TOK/64), dim3(256), 0, stream, dt8, dtw, dtb, delta);
  hipLaunchKernelGGL(k_scan1, dim3(NCHUNK, 8), dim3(64), 0, stream, delta, bxs, Bm, alog, Pc, HcCr);
  hipLaunchKernelGGL(k_carry, dim3(64), dim3(64), 0, stream, Pc, HcCr);
  hipLaunchKernelGGL(k_scan2, dim3(NCHUNK, 8), dim3(64), 0, stream, delta, bxs, Bm, Cm, bsz, alog, dpar, HcCr, yb);
  hipLaunchKernelGGL((k_mfma<2,4,0>), dim3(N_TOK/64, 1), dim3(256), 0, stream,
                     yb, opwt, 256, (const float*)nullptr, feat, t1, (float*)nullptr, 128);
  hipLaunchKernelGGL(k_ln_bf16, dim3(N_TOK/4), dim3(256), 0, stream, t1, lng, lnb, (unsigned*)cat, 128, 0);
  hipLaunchKernelGGL((k_mfma<2,4,0>), dim3(N_TOK/64, 1), dim3(256), 0, stream,
                     cat, w1t, 256, b1, (const float*)nullptr, t1, (float*)nullptr, 128);
  hipLaunchKernelGGL(k_ln_bf16, dim3(N_TOK/4), dim3(256), 0, stream, t1, lag, lab, (unsigned*)h1, 64, 1);
  hipLaunchKernelGGL((k_mfma<2,4,0>), dim3(N_TOK/64, 1), dim3(256), 0, stream,
                     h1, w2t, 128, b2, (const float*)nullptr, out, (float*)nullptr, 128);
}